// Round 7
// baseline (475.783 us; speedup 1.0000x reference)
//
#include <hip/hip_runtime.h>
#include <hip/hip_bf16.h>

#define B_ 4
#define S_ 2048
#define D_ 1024
#define F_ 4096

typedef short bf16x8 __attribute__((ext_vector_type(8)));
typedef float f32x4 __attribute__((ext_vector_type(4)));

static __device__ __forceinline__ unsigned short f2bf(float f) {
    union { float f; unsigned int u; } v; v.f = f;
    unsigned int u = v.u + 0x7FFF + ((v.u >> 16) & 1);  // RNE
    return (unsigned short)(u >> 16);
}
static __device__ __forceinline__ float bf2f(unsigned short u) {
    union { unsigned int u; float f; } v; v.u = ((unsigned int)u) << 16;
    return v.f;
}

// async global->LDS, 16B per lane. LDS dest is wave-uniform base + lane*16.
typedef const __attribute__((address_space(1))) unsigned int* gp_t;
typedef __attribute__((address_space(3))) unsigned int* lp_t;
static __device__ __forceinline__ void gld16(const unsigned short* g, unsigned short* l) {
    __builtin_amdgcn_global_load_lds((gp_t)g, (lp_t)l, 16, 0, 0);
}

// s_waitcnt with selected counters masked off (gfx9 encoding:
// vmcnt[3:0]|[15:14], expcnt[6:4], lgkmcnt[11:8])
#define WAIT_VM8()   __builtin_amdgcn_s_waitcnt(0x0F78)
#define WAIT_VM6()   __builtin_amdgcn_s_waitcnt(0x0F76)
#define WAIT_VM0()   __builtin_amdgcn_s_waitcnt(0x0F70)

// ---------------- transpose fp32 (R x C) -> bf16 (C x R) ----------------
__global__ __launch_bounds__(256) void k_transpose_f32_bf16(
    const float* __restrict__ in, unsigned short* __restrict__ out, int R, int C) {
    __shared__ float t[32][33];
    int c0 = blockIdx.x * 32, r0 = blockIdx.y * 32;
    int x = threadIdx.x, y = threadIdx.y;  // 32 x 8
#pragma unroll
    for (int i = 0; i < 4; i++)
        t[y + 8 * i][x] = in[(size_t)(r0 + y + 8 * i) * C + c0 + x];
    __syncthreads();
#pragma unroll
    for (int i = 0; i < 4; i++)
        out[(size_t)(c0 + y + 8 * i) * R + r0 + x] = f2bf(t[x][y + 8 * i]);
}

// QKV weight transposes fused: z picks source, writes QKVwT + z*D*D (each D x D)
__global__ __launch_bounds__(256) void k_transpose_w3(
    const float* __restrict__ Qw, const float* __restrict__ Kw, const float* __restrict__ Vw,
    unsigned short* __restrict__ out) {
    __shared__ float t[32][33];
    int z = blockIdx.z;
    const float* in = (z == 0) ? Qw : (z == 1) ? Kw : Vw;
    out += (size_t)z * D_ * D_;
    int c0 = blockIdx.x * 32, r0 = blockIdx.y * 32;
    int x = threadIdx.x, y = threadIdx.y;
#pragma unroll
    for (int i = 0; i < 4; i++)
        t[y + 8 * i][x] = in[(size_t)(r0 + y + 8 * i) * D_ + c0 + x];
    __syncthreads();
#pragma unroll
    for (int i = 0; i < 4; i++)
        out[(size_t)(c0 + y + 8 * i) * D_ + r0 + x] = f2bf(t[x][y + 8 * i]);
}

// ---------------- strided bf16 transpose: in (R x C, ldin, batch szin) -> out (C x R, ldout, szout)
__global__ __launch_bounds__(256) void k_transpose_bf16(
    const unsigned short* __restrict__ in, unsigned short* __restrict__ out,
    int ldin, int ldout, long long szin, long long szout) {
    __shared__ unsigned short t[32][33];
    in += (long long)blockIdx.z * szin;
    out += (long long)blockIdx.z * szout;
    int c0 = blockIdx.x * 32, r0 = blockIdx.y * 32;
    int x = threadIdx.x, y = threadIdx.y;
#pragma unroll
    for (int i = 0; i < 4; i++)
        t[y + 8 * i][x] = in[(size_t)(r0 + y + 8 * i) * ldin + c0 + x];
    __syncthreads();
#pragma unroll
    for (int i = 0; i < 4; i++)
        out[(size_t)(c0 + y + 8 * i) * ldout + r0 + x] = t[x][y + 8 * i];
}

// ---------------- layernorm: fp32 row (D_) -> bf16 row ----------------
__global__ __launch_bounds__(256) void k_layernorm(
    const float* __restrict__ x, const float* __restrict__ gamma,
    const float* __restrict__ beta, unsigned short* __restrict__ out) {
    int row = blockIdx.x;
    int t = threadIdx.x;
    const float* xr = x + (size_t)row * D_;
    float4 v = ((const float4*)xr)[t];
    float s = v.x + v.y + v.z + v.w;
    float q = v.x * v.x + v.y * v.y + v.z * v.z + v.w * v.w;
#pragma unroll
    for (int off = 32; off; off >>= 1) {
        s += __shfl_down(s, off);
        q += __shfl_down(q, off);
    }
    __shared__ float ls[4], lq[4];
    int wv = t >> 6;
    if ((t & 63) == 0) { ls[wv] = s; lq[wv] = q; }
    __syncthreads();
    if (t == 0) {
        float S = ls[0] + ls[1] + ls[2] + ls[3];
        float Q = lq[0] + lq[1] + lq[2] + lq[3];
        float mean = S * (1.0f / D_);
        float var = Q * (1.0f / D_) - mean * mean;
        ls[0] = mean; lq[0] = rsqrtf(var + 1e-5f);
    }
    __syncthreads();
    float mean = ls[0], rstd = lq[0];
    float4 g = ((const float4*)gamma)[t];
    float4 b = ((const float4*)beta)[t];
    ushort4 o;
    o.x = f2bf(g.x * (v.x - mean) * rstd + b.x);
    o.y = f2bf(g.y * (v.y - mean) * rstd + b.y);
    o.z = f2bf(g.z * (v.z - mean) * rstd + b.z);
    o.w = f2bf(g.w * (v.w - mean) * rstd + b.w);
    ((ushort4*)(out + (size_t)row * D_))[t] = o;
}

// ---------------- causal softmax, in-place on bf16 scores rows ----------------
// Vectorized 16B/lane (bf16x8); thread t owns elems 8t..8t+7.
// Causal truncation: read only j < valid; write only j < roundup(valid,128)
// (PV's klimit reads exactly k < (bm+1)*128 = roundup(valid,128) for every row
// in its block, and the scores GEMM never writes upper-tri 128-blocks, so bytes
// beyond wlim are never produced or consumed).
__global__ __launch_bounds__(256) void k_softmax(unsigned short* __restrict__ sp) {
    int r = blockIdx.x;          // global row in [0, B_*S_)
    int i = r & (S_ - 1);        // query index within batch
    unsigned short* row = sp + (size_t)r * S_;
    int t = threadIdx.x;
    int valid = i + 1;
    int wlim = (valid + 127) & ~127;  // multiple of 128 (and of 8)
    bf16x8 v8 = {};
    if (t * 8 < valid) v8 = *(const bf16x8*)(row + t * 8);
    float vals[8];
    float mx = -1e30f;
#pragma unroll
    for (int k = 0; k < 8; k++) {
        int j = t * 8 + k;
        vals[k] = (j < valid) ? bf2f((unsigned short)v8[k]) : -1e30f;
        mx = fmaxf(mx, vals[k]);
    }
#pragma unroll
    for (int off = 32; off; off >>= 1) mx = fmaxf(mx, __shfl_xor(mx, off));
    __shared__ float red[4];
    if ((t & 63) == 0) red[t >> 6] = mx;
    __syncthreads();
    mx = fmaxf(fmaxf(red[0], red[1]), fmaxf(red[2], red[3]));
    __syncthreads();
    float e[8];
    float sum = 0.f;
#pragma unroll
    for (int k = 0; k < 8; k++) {
        int j = t * 8 + k;
        e[k] = (j < valid) ? __expf(vals[k] - mx) : 0.f;
        sum += e[k];
    }
#pragma unroll
    for (int off = 32; off; off >>= 1) sum += __shfl_xor(sum, off);
    if ((t & 63) == 0) red[t >> 6] = sum;
    __syncthreads();
    sum = red[0] + red[1] + red[2] + red[3];
    float inv = 1.0f / sum;
    if (t * 8 < wlim) {
        bf16x8 o8;
#pragma unroll
        for (int k = 0; k < 8; k++) o8[k] = (short)f2bf(e[k] * inv);
        *(bf16x8*)(row + t * 8) = o8;
    }
}

// ---------------- GEMM (legacy 128x128, 2-phase counted-vmcnt) ----------------
// Used for scores (causal block-skip), PV (klimit), FFN2 (N=1024). 64KB LDS ->
// 2 blocks/CU: cross-block TLP fills barrier gaps — empirically beats every
// 1-block/CU deep schedule tried for low-occupancy / skinny shapes (rounds 3-5).
template <int EPI>
__global__ __launch_bounds__(256) void k_gemm_bt(
    const unsigned short* __restrict__ A, const unsigned short* __restrict__ Bt,
    void* __restrict__ Cv, const float* __restrict__ bias, const float* __restrict__ res,
    int K, int lda, int ldb, int ldc,
    long long sA, long long sB, long long sC, float scale, int klimit, int swz) {
    int bn, bm, z;
    if (swz > 0) {
        int GN = gridDim.x, GM = gridDim.y;
        int L = blockIdx.x + GN * (blockIdx.y + GM * blockIdx.z);
        int rows = gridDim.y * gridDim.z;
        int xcd = L & 7;
        int s = L >> 3;
        int bng = GN / swz;
        int rpg = rows * swz / 8;
        int xg = xcd % swz, yg = xcd / swz;
        int bnl = s % bng;
        int rl = s / bng;
        int row = yg * rpg + rl;
        bn = xg * bng + bnl;
        bm = row % GM;
        z = row / GM;
    } else {
        bn = blockIdx.x; bm = blockIdx.y; z = blockIdx.z;
    }
    if (EPI == 1 && bn > bm) return;
    A += (long long)z * sA;
    Bt += (long long)z * sB;
    long long coff = (long long)z * sC;
    float* Cf = (float*)Cv;
    unsigned short* Cb = (unsigned short*)Cv;

    __shared__ unsigned short As[2][2][128 * 32];
    __shared__ unsigned short Bs[2][2][128 * 32];

    int t = threadIdx.x;
    int l = t & 63, w = t >> 6;
    int wm = (w & 1) * 64, wn = (w >> 1) * 64;
    int lr = l & 15, lq = l >> 4;

    f32x4 acc[4][4];
#pragma unroll
    for (int i = 0; i < 4; i++)
#pragma unroll
        for (int j = 0; j < 4; j++) acc[i][j] = (f32x4){0.f, 0.f, 0.f, 0.f};

    int kend = K;
    if (klimit) { int ke = (bm + 1) * 128; kend = ke < K ? ke : K; }

    int sr = l >> 2;
    int sc = (l & 3) * 8;
    const unsigned short* gA0 = A + (size_t)(bm * 128 + w * 32 + sr) * lda + sc;
    const unsigned short* gA1 = gA0 + (size_t)16 * lda;
    const unsigned short* gB0 = Bt + (size_t)(bn * 128 + w * 32 + sr) * ldb + sc;
    const unsigned short* gB1 = gB0 + (size_t)16 * ldb;

    auto stage = [&](int buf, int k0) {
#pragma unroll
        for (int kc = 0; kc < 2; kc++) {
            int kk = k0 + kc * 32;
            gld16(gA0 + kk, &As[buf][kc][(w * 32) * 32]);
            gld16(gA1 + kk, &As[buf][kc][(w * 32 + 16) * 32]);
            gld16(gB0 + kk, &Bs[buf][kc][(w * 32) * 32]);
            gld16(gB1 + kk, &Bs[buf][kc][(w * 32 + 16) * 32]);
        }
    };

    int NB = kend >> 6;
    stage(0, 0);
    for (int it = 0; it < NB; it++) {
        int cur = it & 1;
        if (it + 1 < NB) {
            stage(1 - cur, (it + 1) * 64);
            WAIT_VM8();
        } else {
            WAIT_VM0();
        }
        __builtin_amdgcn_s_barrier();
#pragma unroll
        for (int kc = 0; kc < 2; kc++) {
            bf16x8 af[4], bf[4];
#pragma unroll
            for (int i = 0; i < 4; i++)
                af[i] = *(const bf16x8*)(&As[cur][kc][(wm + i * 16 + lr) * 32 + lq * 8]);
#pragma unroll
            for (int j = 0; j < 4; j++)
                bf[j] = *(const bf16x8*)(&Bs[cur][kc][(wn + j * 16 + lr) * 32 + lq * 8]);
#pragma unroll
            for (int i = 0; i < 4; i++)
#pragma unroll
                for (int j = 0; j < 4; j++)
                    acc[i][j] = __builtin_amdgcn_mfma_f32_16x16x32_bf16(af[i], bf[j], acc[i][j], 0, 0, 0);
        }
        __builtin_amdgcn_s_barrier();
    }

#pragma unroll
    for (int i = 0; i < 4; i++) {
        int mbase = bm * 128 + wm + i * 16 + lq * 4;
#pragma unroll
        for (int j = 0; j < 4; j++) {
            int n = bn * 128 + wn + j * 16 + lr;
#pragma unroll
            for (int r = 0; r < 4; r++) {
                int m = mbase + r;
                float v = acc[i][j][r];
                long long idx = coff + (long long)m * ldc + n;
                if (EPI == 0) {
                    Cb[idx] = f2bf(v);
                } else if (EPI == 1) {
                    Cb[idx] = f2bf(v * scale);
                } else if (EPI == 2) {
                    Cf[idx] = v + res[idx];
                } else if (EPI == 3) {
                    float u = v + bias[n];
                    Cb[idx] = f2bf(u > 0.f ? u : 0.f);
                } else {
                    Cf[idx] = v + bias[n] + res[idx];
                }
            }
        }
    }
}

// ---------------- GEMM 256x256, 8-wave, BK=64, 4-phase/K-tile ----------------
// (verified round 2) T2 3-bit XOR swizzle both-sides, T3+T4 counted vmcnt(6),
// T5 setprio. Used for QKV / FFN1 — grids >= 384 blocks, >= 1 full round of
// 1-block/CU occupancy. NOT for low-occupancy shapes (scores: 144 active
// blocks -> half-idle GPU; rounds 3-5 showed this schedule collapses there).
template <int EPI>
__global__ __launch_bounds__(512, 2) void k_gemm256(
    const unsigned short* __restrict__ A, const unsigned short* __restrict__ Bt,
    void* __restrict__ Cv, const float* __restrict__ bias, const float* __restrict__ res,
    int K, int lda, int ldb, int ldc,
    long long sA, long long sB, long long sC, float scale, int klimit) {
    int bn = blockIdx.x, bm = blockIdx.y, z = blockIdx.z;
    if (EPI == 1 && bn > bm) return;  // fully-masked causal block
    A += (long long)z * sA;
    Bt += (long long)z * sB;
    long long coff = (long long)z * sC;
    float* Cf = (float*)Cv;
    unsigned short* Cb = (unsigned short*)Cv;

    __shared__ unsigned short As[2][2][128 * 64];
    __shared__ unsigned short Bs[2][2][128 * 64];

    int t = threadIdx.x;
    int l = t & 63, w = t >> 6;       // lane, wave 0..7 (2M x 4N)
    int wmh = w >> 2;                 // which A half this wave reads
    int wnh = (w >> 1) & 1;           // which B half this wave reads
    int bnl = (w & 1) * 64;           // row base within that B half
    int lr = l & 15, lq = l >> 4;
    int rx = (lr & 7) << 3;           // read-side swizzle XOR (elems)
    int c0 = lq * 8;                  // un-swizzled k-subcolumn (elems)

    f32x4 acc[8][4];
#pragma unroll
    for (int i = 0; i < 8; i++)
#pragma unroll
        for (int j = 0; j < 4; j++) acc[i][j] = (f32x4){0.f, 0.f, 0.f, 0.f};

    int kend = K;
    if (klimit) { int ke = (bm + 1) * 256; kend = ke < K ? ke : K; }
    int NB = kend >> 6;

    int grow = l >> 3;
    int gcol = ((l & 7) * 8) ^ (((l >> 3) & 7) << 3);
    const unsigned short* gA = A + (size_t)(bm * 256 + w * 16 + grow) * lda + gcol;
    const unsigned short* gB = Bt + (size_t)(bn * 256 + w * 16 + grow) * ldb + gcol;

    auto stageA = [&](int buf, int half, int k0) {
        const unsigned short* g = gA + (size_t)(half * 128) * lda + k0;
        unsigned short* s = &As[buf][half][(w * 16) * 64];
        gld16(g, s);
        gld16(g + (size_t)8 * lda, s + 8 * 64);
    };
    auto stageB = [&](int buf, int half, int k0) {
        const unsigned short* g = gB + (size_t)(half * 128) * ldb + k0;
        unsigned short* s = &Bs[buf][half][(w * 16) * 64];
        gld16(g, s);
        gld16(g + (size_t)8 * ldb, s + 8 * 64);
    };

    stageA(0, 0, 0); stageA(0, 1, 0);
    stageB(0, 0, 0); stageB(0, 1, 0);
    int kp = (NB > 1) ? 64 : 0;
    stageB(1, 0, kp); stageB(1, 1, kp); stageA(1, 0, kp);
    WAIT_VM6();
    __builtin_amdgcn_s_barrier();

    bf16x8 aF0[2][4], aF1[2][4], bF[2][4];  // [kchunk][frag]

    for (int j = 0; j < NB; j++) {
        int b = j & 1;
        int k1 = ((j + 1 < NB) ? (j + 1) : (NB - 1)) << 6;
        int k2 = ((j + 2 < NB) ? (j + 2) : (NB - 1)) << 6;
        const unsigned short* Ah = &As[b][wmh][0];
        const unsigned short* Bh = &Bs[b][wnh][0];

        // ---- P1 ----
#pragma unroll
        for (int kc = 0; kc < 2; kc++) {
#pragma unroll
            for (int f = 0; f < 4; f++)
                bF[kc][f] = *(const bf16x8*)(Bh + (bnl + f * 16 + lr) * 64 + ((kc * 32 + c0) ^ rx));
#pragma unroll
            for (int f = 0; f < 4; f++)
                aF0[kc][f] = *(const bf16x8*)(Ah + (f * 16 + lr) * 64 + ((kc * 32 + c0) ^ rx));
        }
        stageA(b ^ 1, 1, k1);
        __builtin_amdgcn_s_barrier();
        __builtin_amdgcn_s_setprio(1);
#pragma unroll
        for (int kc = 0; kc < 2; kc++)
#pragma unroll
            for (int i = 0; i < 4; i++)
#pragma unroll
                for (int jn = 0; jn < 2; jn++)
                    acc[i][jn] = __builtin_amdgcn_mfma_f32_16x16x32_bf16(
                        aF0[kc][i], bF[kc][jn], acc[i][jn], 0, 0, 0);
        __builtin_amdgcn_s_setprio(0);
        __builtin_amdgcn_s_barrier();

        // ---- P2 ----
#pragma unroll
        for (int kc = 0; kc < 2; kc++)
#pragma unroll
            for (int f = 0; f < 4; f++)
                aF1[kc][f] = *(const bf16x8*)(Ah + (64 + f * 16 + lr) * 64 + ((kc * 32 + c0) ^ rx));
        stageB(b, 0, k2);
        __builtin_amdgcn_s_barrier();
        __builtin_amdgcn_s_setprio(1);
#pragma unroll
        for (int kc = 0; kc < 2; kc++)
#pragma unroll
            for (int i = 0; i < 4; i++)
#pragma unroll
                for (int jn = 0; jn < 2; jn++)
                    acc[4 + i][jn] = __builtin_amdgcn_mfma_f32_16x16x32_bf16(
                        aF1[kc][i], bF[kc][jn], acc[4 + i][jn], 0, 0, 0);
        __builtin_amdgcn_s_setprio(0);
        __builtin_amdgcn_s_barrier();

        // ---- P3 ----
        stageB(b, 1, k2);
        __builtin_amdgcn_s_barrier();
        __builtin_amdgcn_s_setprio(1);
#pragma unroll
        for (int kc = 0; kc < 2; kc++)
#pragma unroll
            for (int i = 0; i < 4; i++)
#pragma unroll
                for (int jn = 0; jn < 2; jn++)
                    acc[4 + i][2 + jn] = __builtin_amdgcn_mfma_f32_16x16x32_bf16(
                        aF1[kc][i], bF[kc][2 + jn], acc[4 + i][2 + jn], 0, 0, 0);
        __builtin_amdgcn_s_setprio(0);
        __builtin_amdgcn_s_barrier();

        // ---- P4 ----
        stageA(b, 0, k2);
        WAIT_VM6();
        __builtin_amdgcn_s_barrier();
        __builtin_amdgcn_s_setprio(1);
#pragma unroll
        for (int kc = 0; kc < 2; kc++)
#pragma unroll
            for (int i = 0; i < 4; i++)
#pragma unroll
                for (int jn = 0; jn < 2; jn++)
                    acc[i][2 + jn] = __builtin_amdgcn_mfma_f32_16x16x32_bf16(
                        aF0[kc][i], bF[kc][2 + jn], acc[i][2 + jn], 0, 0, 0);
        __builtin_amdgcn_s_setprio(0);
        __builtin_amdgcn_s_barrier();
    }
    WAIT_VM0();

#pragma unroll
    for (int i = 0; i < 8; i++) {
        int mbase = bm * 256 + wmh * 128 + i * 16 + lq * 4;
#pragma unroll
        for (int jn = 0; jn < 4; jn++) {
            int n = bn * 256 + (w & 3) * 64 + jn * 16 + lr;
#pragma unroll
            for (int r = 0; r < 4; r++) {
                int m = mbase + r;
                float v = acc[i][jn][r];
                long long idx = coff + (long long)m * ldc + n;
                if (EPI == 0) {
                    Cb[idx] = f2bf(v);
                } else if (EPI == 1) {
                    Cb[idx] = f2bf(v * scale);
                } else if (EPI == 2) {
                    Cf[idx] = v + res[idx];
                } else if (EPI == 3) {
                    float u = v + bias[n];
                    Cb[idx] = f2bf(u > 0.f ? u : 0.f);
                } else {  // EPI == 4
                    Cf[idx] = v + bias[n] + res[idx];
                }
            }
        }
    }
}

extern "C" void kernel_launch(void* const* d_in, const int* in_sizes, int n_in,
                              void* d_out, int out_size, void* d_ws, size_t ws_size,
                              hipStream_t stream) {
    const float* x      = (const float*)d_in[0];
    const float* Qw     = (const float*)d_in[1];
    const float* Kw     = (const float*)d_in[2];
    const float* Vw     = (const float*)d_in[3];
    const float* w1     = (const float*)d_in[4];
    const float* b1     = (const float*)d_in[5];
    const float* w2     = (const float*)d_in[6];
    const float* b2     = (const float*)d_in[7];
    const float* gamma1 = (const float*)d_in[8];
    const float* beta1  = (const float*)d_in[9];
    const float* gamma2 = (const float*)d_in[10];
    const float* beta2  = (const float*)d_in[11];
    float* out = (float*)d_out;

    char* ws = (char*)d_ws;
    size_t off = 0;
    auto alloc = [&](size_t bytes) -> void* {
        void* p = ws + off;
        off += (bytes + 255) & ~(size_t)255;
        return p;
    };
    const size_t MN = (size_t)B_ * S_ * D_;  // 8.4M elems
    unsigned short* xn     = (unsigned short*)alloc(MN * 2);                     // 16.8MB
    unsigned short* scoreP = (unsigned short*)alloc((size_t)B_ * S_ * S_ * 2);   // 33.6MB, scores->P in place
    unsigned short* qkv    = (unsigned short*)alloc((size_t)B_ * S_ * 3072 * 2); // 50.3MB interleaved Q|K|V
    unsigned short* VT     = (unsigned short*)alloc(MN * 2);                     // 16.8MB
    unsigned short* QKVwT  = (unsigned short*)alloc((size_t)3 * D_ * D_ * 2);    // 6.3MB
    unsigned short* w1T    = (unsigned short*)alloc((size_t)D_ * F_ * 2);        // 8.4MB
    unsigned short* w2T    = (unsigned short*)alloc((size_t)F_ * D_ * 2);        // 8.4MB
    // mid (8192 x 4096 bf16 = 67,108,864 B) overlays qkv+VT (dead after PV).
    unsigned short* mid = qkv;

    dim3 tb(32, 8);
    // weight conversion (transposed so all GEMMs take Bt = N x K)
    k_transpose_w3<<<dim3(D_ / 32, D_ / 32, 3), tb, 0, stream>>>(Qw, Kw, Vw, QKVwT);
    k_transpose_f32_bf16<<<dim3(F_ / 32, D_ / 32), tb, 0, stream>>>(w1, w1T, D_, F_);
    k_transpose_f32_bf16<<<dim3(D_ / 32, F_ / 32), tb, 0, stream>>>(w2, w2T, F_, D_);

    // LN1
    k_layernorm<<<B_ * S_, 256, 0, stream>>>(x, gamma1, beta1, xn);

    // fused QKV projection: M = 8192, N = 3072, K = 1024 -> qkv row-major (ldc 3072)
    const int Mtok = B_ * S_;
    k_gemm256<0><<<dim3(3072 / 256, Mtok / 256), 512, 0, stream>>>(
        xn, QKVwT, qkv, nullptr, nullptr, D_, D_, D_, 3072, 0, 0, 0, 1.f, 0);

    // V transpose per batch: (S x D, ld 3072) -> VT (D x S)
    k_transpose_bf16<<<dim3(D_ / 32, S_ / 32, B_), tb, 0, stream>>>(
        qkv + 2048, VT, 3072, S_, (long long)S_ * 3072, (long long)D_ * S_);

    // scores = Q @ K^T / 32 (batched, bf16 out), upper-tri 128-blocks skipped.
    // Legacy 128^2 kernel: 544 active blocks ~2.1/CU (k_gemm256 here leaves
    // 44% of CUs idle at 1 block/CU -- its worst regime, rounds 3-5).
    k_gemm_bt<1><<<dim3(S_ / 128, S_ / 128, B_), 256, 0, stream>>>(
        qkv, qkv + 1024, scoreP, nullptr, nullptr, D_, 3072, 3072, S_,
        (long long)S_ * 3072, (long long)S_ * 3072, (long long)S_ * S_, 0.03125f, 0, 4);

    // causal softmax in place -> P (bf16), truncated to lower-tri + pad
    k_softmax<<<B_ * S_, 256, 0, stream>>>(scoreP);

    // attn = P @ V + x -> out (fp32); K-loop truncated at diagonal (mult of 64)
    k_gemm_bt<2><<<dim3(D_ / 128, S_ / 128, B_), 256, 0, stream>>>(
        scoreP, VT, out, nullptr, x, S_, S_, S_, D_,
        (long long)S_ * S_, (long long)D_ * S_, (long long)S_ * D_, 1.f, 1, 2);

    // LN2 on out -> xn (h)
    k_layernorm<<<B_ * S_, 256, 0, stream>>>(out, gamma2, beta2, xn);

    // mid = relu(h @ w1 + b1) (bf16), 256^2 4-phase: grid 16x32 = 512 blocks
    k_gemm256<3><<<dim3(F_ / 256, Mtok / 256), 512, 0, stream>>>(
        xn, w1T, mid, b1, nullptr, D_, D_, D_, F_, 0, 0, 0, 1.f, 0);

    // out = out + mid @ w2 + b2 (legacy 128^2, 2 blocks/CU — best known for
    // this shape; rounds 3-5 A/B'd three deeper 1-block/CU schedules, all lost)
    k_gemm_bt<4><<<dim3(D_ / 128, Mtok / 128), 256, 0, stream>>>(
        mid, w2T, out, b2, out, F_, F_, F_, D_, 0, 0, 0, 1.f, 0, 2);
}

// Round 8
// 466.478 us; speedup vs baseline: 1.0199x; 1.0199x over previous
//
#include <hip/hip_runtime.h>
#include <hip/hip_bf16.h>

#define B_ 4
#define S_ 2048
#define D_ 1024
#define F_ 4096

typedef short bf16x8 __attribute__((ext_vector_type(8)));
typedef float f32x4 __attribute__((ext_vector_type(4)));

static __device__ __forceinline__ unsigned short f2bf(float f) {
    union { float f; unsigned int u; } v; v.f = f;
    unsigned int u = v.u + 0x7FFF + ((v.u >> 16) & 1);  // RNE
    return (unsigned short)(u >> 16);
}
static __device__ __forceinline__ float bf2f(unsigned short u) {
    union { unsigned int u; float f; } v; v.u = ((unsigned int)u) << 16;
    return v.f;
}

// async global->LDS, 16B per lane. LDS dest is wave-uniform base + lane*16.
typedef const __attribute__((address_space(1))) unsigned int* gp_t;
typedef __attribute__((address_space(3))) unsigned int* lp_t;
static __device__ __forceinline__ void gld16(const unsigned short* g, unsigned short* l) {
    __builtin_amdgcn_global_load_lds((gp_t)g, (lp_t)l, 16, 0, 0);
}

// s_waitcnt with selected counters masked off (gfx9 encoding:
// vmcnt[3:0]|[15:14], expcnt[6:4], lgkmcnt[11:8])
#define WAIT_VM8()   __builtin_amdgcn_s_waitcnt(0x0F78)
#define WAIT_VM6()   __builtin_amdgcn_s_waitcnt(0x0F76)
#define WAIT_VM0()   __builtin_amdgcn_s_waitcnt(0x0F70)

// ---------------- transpose fp32 (R x C) -> bf16 (C x R) ----------------
__global__ __launch_bounds__(256) void k_transpose_f32_bf16(
    const float* __restrict__ in, unsigned short* __restrict__ out, int R, int C) {
    __shared__ float t[32][33];
    int c0 = blockIdx.x * 32, r0 = blockIdx.y * 32;
    int x = threadIdx.x, y = threadIdx.y;  // 32 x 8
#pragma unroll
    for (int i = 0; i < 4; i++)
        t[y + 8 * i][x] = in[(size_t)(r0 + y + 8 * i) * C + c0 + x];
    __syncthreads();
#pragma unroll
    for (int i = 0; i < 4; i++)
        out[(size_t)(c0 + y + 8 * i) * R + r0 + x] = f2bf(t[x][y + 8 * i]);
}

// QKV weight transposes fused: z picks source, writes QKVwT + z*D*D (each D x D)
__global__ __launch_bounds__(256) void k_transpose_w3(
    const float* __restrict__ Qw, const float* __restrict__ Kw, const float* __restrict__ Vw,
    unsigned short* __restrict__ out) {
    __shared__ float t[32][33];
    int z = blockIdx.z;
    const float* in = (z == 0) ? Qw : (z == 1) ? Kw : Vw;
    out += (size_t)z * D_ * D_;
    int c0 = blockIdx.x * 32, r0 = blockIdx.y * 32;
    int x = threadIdx.x, y = threadIdx.y;
#pragma unroll
    for (int i = 0; i < 4; i++)
        t[y + 8 * i][x] = in[(size_t)(r0 + y + 8 * i) * D_ + c0 + x];
    __syncthreads();
#pragma unroll
    for (int i = 0; i < 4; i++)
        out[(size_t)(c0 + y + 8 * i) * D_ + r0 + x] = f2bf(t[x][y + 8 * i]);
}

// ---------------- layernorm: fp32 row (D_) -> bf16 row ----------------
__global__ __launch_bounds__(256) void k_layernorm(
    const float* __restrict__ x, const float* __restrict__ gamma,
    const float* __restrict__ beta, unsigned short* __restrict__ out) {
    int row = blockIdx.x;
    int t = threadIdx.x;
    const float* xr = x + (size_t)row * D_;
    float4 v = ((const float4*)xr)[t];
    float s = v.x + v.y + v.z + v.w;
    float q = v.x * v.x + v.y * v.y + v.z * v.z + v.w * v.w;
#pragma unroll
    for (int off = 32; off; off >>= 1) {
        s += __shfl_down(s, off);
        q += __shfl_down(q, off);
    }
    __shared__ float ls[4], lq[4];
    int wv = t >> 6;
    if ((t & 63) == 0) { ls[wv] = s; lq[wv] = q; }
    __syncthreads();
    if (t == 0) {
        float S = ls[0] + ls[1] + ls[2] + ls[3];
        float Q = lq[0] + lq[1] + lq[2] + lq[3];
        float mean = S * (1.0f / D_);
        float var = Q * (1.0f / D_) - mean * mean;
        ls[0] = mean; lq[0] = rsqrtf(var + 1e-5f);
    }
    __syncthreads();
    float mean = ls[0], rstd = lq[0];
    float4 g = ((const float4*)gamma)[t];
    float4 b = ((const float4*)beta)[t];
    ushort4 o;
    o.x = f2bf(g.x * (v.x - mean) * rstd + b.x);
    o.y = f2bf(g.y * (v.y - mean) * rstd + b.y);
    o.z = f2bf(g.z * (v.z - mean) * rstd + b.z);
    o.w = f2bf(g.w * (v.w - mean) * rstd + b.w);
    ((ushort4*)(out + (size_t)row * D_))[t] = o;
}

// ---------------- causal softmax, in-place on bf16 scores rows ----------------
// Vectorized 16B/lane (bf16x8); thread t owns elems 8t..8t+7.
// Causal truncation: read only j < valid; write only j < roundup(valid,128)
// (PV's klimit reads exactly k < (bm+1)*128 = roundup(valid,128) for every row
// in its block, and the scores GEMM never writes upper-tri 128-blocks, so bytes
// beyond wlim are never produced or consumed).
__global__ __launch_bounds__(256) void k_softmax(unsigned short* __restrict__ sp) {
    int r = blockIdx.x;          // global row in [0, B_*S_)
    int i = r & (S_ - 1);        // query index within batch
    unsigned short* row = sp + (size_t)r * S_;
    int t = threadIdx.x;
    int valid = i + 1;
    int wlim = (valid + 127) & ~127;  // multiple of 128 (and of 8)
    bf16x8 v8 = {};
    if (t * 8 < valid) v8 = *(const bf16x8*)(row + t * 8);
    float vals[8];
    float mx = -1e30f;
#pragma unroll
    for (int k = 0; k < 8; k++) {
        int j = t * 8 + k;
        vals[k] = (j < valid) ? bf2f((unsigned short)v8[k]) : -1e30f;
        mx = fmaxf(mx, vals[k]);
    }
#pragma unroll
    for (int off = 32; off; off >>= 1) mx = fmaxf(mx, __shfl_xor(mx, off));
    __shared__ float red[4];
    if ((t & 63) == 0) red[t >> 6] = mx;
    __syncthreads();
    mx = fmaxf(fmaxf(red[0], red[1]), fmaxf(red[2], red[3]));
    __syncthreads();
    float e[8];
    float sum = 0.f;
#pragma unroll
    for (int k = 0; k < 8; k++) {
        int j = t * 8 + k;
        e[k] = (j < valid) ? __expf(vals[k] - mx) : 0.f;
        sum += e[k];
    }
#pragma unroll
    for (int off = 32; off; off >>= 1) sum += __shfl_xor(sum, off);
    if ((t & 63) == 0) red[t >> 6] = sum;
    __syncthreads();
    sum = red[0] + red[1] + red[2] + red[3];
    float inv = 1.0f / sum;
    if (t * 8 < wlim) {
        bf16x8 o8;
#pragma unroll
        for (int k = 0; k < 8; k++) o8[k] = (short)f2bf(e[k] * inv);
        *(bf16x8*)(row + t * 8) = o8;
    }
}

// ---------------- GEMM (legacy 128x128, 2-phase counted-vmcnt) ----------------
// Used for PV (klimit) and FFN2 (N=1024). 64KB LDS -> 2 blocks/CU: cross-block
// TLP fills barrier gaps — empirically beats every 1-block/CU deep schedule
// tried for long-K skinny shapes (rounds 3-5).
template <int EPI>
__global__ __launch_bounds__(256) void k_gemm_bt(
    const unsigned short* __restrict__ A, const unsigned short* __restrict__ Bt,
    void* __restrict__ Cv, const float* __restrict__ bias, const float* __restrict__ res,
    int K, int lda, int ldb, int ldc,
    long long sA, long long sB, long long sC, float scale, int klimit, int swz) {
    int bn, bm, z;
    if (swz > 0) {
        int GN = gridDim.x, GM = gridDim.y;
        int L = blockIdx.x + GN * (blockIdx.y + GM * blockIdx.z);
        int rows = gridDim.y * gridDim.z;
        int xcd = L & 7;
        int s = L >> 3;
        int bng = GN / swz;
        int rpg = rows * swz / 8;
        int xg = xcd % swz, yg = xcd / swz;
        int bnl = s % bng;
        int rl = s / bng;
        int row = yg * rpg + rl;
        bn = xg * bng + bnl;
        bm = row % GM;
        z = row / GM;
    } else {
        bn = blockIdx.x; bm = blockIdx.y; z = blockIdx.z;
    }
    if (EPI == 1 && bn > bm) return;
    A += (long long)z * sA;
    Bt += (long long)z * sB;
    long long coff = (long long)z * sC;
    float* Cf = (float*)Cv;
    unsigned short* Cb = (unsigned short*)Cv;

    __shared__ unsigned short As[2][2][128 * 32];
    __shared__ unsigned short Bs[2][2][128 * 32];

    int t = threadIdx.x;
    int l = t & 63, w = t >> 6;
    int wm = (w & 1) * 64, wn = (w >> 1) * 64;
    int lr = l & 15, lq = l >> 4;

    f32x4 acc[4][4];
#pragma unroll
    for (int i = 0; i < 4; i++)
#pragma unroll
        for (int j = 0; j < 4; j++) acc[i][j] = (f32x4){0.f, 0.f, 0.f, 0.f};

    int kend = K;
    if (klimit) { int ke = (bm + 1) * 128; kend = ke < K ? ke : K; }

    int sr = l >> 2;
    int sc = (l & 3) * 8;
    const unsigned short* gA0 = A + (size_t)(bm * 128 + w * 32 + sr) * lda + sc;
    const unsigned short* gA1 = gA0 + (size_t)16 * lda;
    const unsigned short* gB0 = Bt + (size_t)(bn * 128 + w * 32 + sr) * ldb + sc;
    const unsigned short* gB1 = gB0 + (size_t)16 * ldb;

    auto stage = [&](int buf, int k0) {
#pragma unroll
        for (int kc = 0; kc < 2; kc++) {
            int kk = k0 + kc * 32;
            gld16(gA0 + kk, &As[buf][kc][(w * 32) * 32]);
            gld16(gA1 + kk, &As[buf][kc][(w * 32 + 16) * 32]);
            gld16(gB0 + kk, &Bs[buf][kc][(w * 32) * 32]);
            gld16(gB1 + kk, &Bs[buf][kc][(w * 32 + 16) * 32]);
        }
    };

    int NB = kend >> 6;
    stage(0, 0);
    for (int it = 0; it < NB; it++) {
        int cur = it & 1;
        if (it + 1 < NB) {
            stage(1 - cur, (it + 1) * 64);
            WAIT_VM8();
        } else {
            WAIT_VM0();
        }
        __builtin_amdgcn_s_barrier();
#pragma unroll
        for (int kc = 0; kc < 2; kc++) {
            bf16x8 af[4], bf[4];
#pragma unroll
            for (int i = 0; i < 4; i++)
                af[i] = *(const bf16x8*)(&As[cur][kc][(wm + i * 16 + lr) * 32 + lq * 8]);
#pragma unroll
            for (int j = 0; j < 4; j++)
                bf[j] = *(const bf16x8*)(&Bs[cur][kc][(wn + j * 16 + lr) * 32 + lq * 8]);
#pragma unroll
            for (int i = 0; i < 4; i++)
#pragma unroll
                for (int j = 0; j < 4; j++)
                    acc[i][j] = __builtin_amdgcn_mfma_f32_16x16x32_bf16(af[i], bf[j], acc[i][j], 0, 0, 0);
        }
        __builtin_amdgcn_s_barrier();
    }

#pragma unroll
    for (int i = 0; i < 4; i++) {
        int mbase = bm * 128 + wm + i * 16 + lq * 4;
#pragma unroll
        for (int j = 0; j < 4; j++) {
            int n = bn * 128 + wn + j * 16 + lr;
#pragma unroll
            for (int r = 0; r < 4; r++) {
                int m = mbase + r;
                float v = acc[i][j][r];
                long long idx = coff + (long long)m * ldc + n;
                if (EPI == 0) {
                    Cb[idx] = f2bf(v);
                } else if (EPI == 1) {
                    Cb[idx] = f2bf(v * scale);
                } else if (EPI == 2) {
                    Cf[idx] = v + res[idx];
                } else if (EPI == 3) {
                    float u = v + bias[n];
                    Cb[idx] = f2bf(u > 0.f ? u : 0.f);
                } else {
                    Cf[idx] = v + bias[n] + res[idx];
                }
            }
        }
    }
}

// ---------------- GEMM 256x256, 8-wave, BK=64, 4-phase/K-tile ----------------
// (verified round 2) T2 3-bit XOR swizzle both-sides, T3+T4 counted vmcnt(6),
// T5 setprio. Used for QKV / scores / FFN1.
// EPI=6 (new): fused QKV epilogue — Q,K columns (n<2048) stored row-major to C
// (ldc 3072); V columns (n>=2048) stored TRANSPOSED directly to VT (passed via
// res): thread's r=0..3 are 4 consecutive m at fixed n -> one aligned 8B store
// at VT[z][n-2048][m]. Eliminates the separate V-transpose pass (34 MB).
// Branch is wave-uniform per jn (16-wide n-groups, 2048 boundary 16-aligned).
template <int EPI>
__global__ __launch_bounds__(512, 2) void k_gemm256(
    const unsigned short* __restrict__ A, const unsigned short* __restrict__ Bt,
    void* __restrict__ Cv, const float* __restrict__ bias, const float* __restrict__ res,
    int K, int lda, int ldb, int ldc,
    long long sA, long long sB, long long sC, float scale, int klimit) {
    int bn = blockIdx.x, bm = blockIdx.y, z = blockIdx.z;
    if (EPI == 1 && bn > bm) return;  // fully-masked causal block
    A += (long long)z * sA;
    Bt += (long long)z * sB;
    long long coff = (long long)z * sC;
    float* Cf = (float*)Cv;
    unsigned short* Cb = (unsigned short*)Cv;

    __shared__ unsigned short As[2][2][128 * 64];
    __shared__ unsigned short Bs[2][2][128 * 64];

    int t = threadIdx.x;
    int l = t & 63, w = t >> 6;       // lane, wave 0..7 (2M x 4N)
    int wmh = w >> 2;                 // which A half this wave reads
    int wnh = (w >> 1) & 1;           // which B half this wave reads
    int bnl = (w & 1) * 64;           // row base within that B half
    int lr = l & 15, lq = l >> 4;
    int rx = (lr & 7) << 3;           // read-side swizzle XOR (elems)
    int c0 = lq * 8;                  // un-swizzled k-subcolumn (elems)

    f32x4 acc[8][4];
#pragma unroll
    for (int i = 0; i < 8; i++)
#pragma unroll
        for (int j = 0; j < 4; j++) acc[i][j] = (f32x4){0.f, 0.f, 0.f, 0.f};

    int kend = K;
    if (klimit) { int ke = (bm + 1) * 256; kend = ke < K ? ke : K; }
    int NB = kend >> 6;

    int grow = l >> 3;
    int gcol = ((l & 7) * 8) ^ (((l >> 3) & 7) << 3);
    const unsigned short* gA = A + (size_t)(bm * 256 + w * 16 + grow) * lda + gcol;
    const unsigned short* gB = Bt + (size_t)(bn * 256 + w * 16 + grow) * ldb + gcol;

    auto stageA = [&](int buf, int half, int k0) {
        const unsigned short* g = gA + (size_t)(half * 128) * lda + k0;
        unsigned short* s = &As[buf][half][(w * 16) * 64];
        gld16(g, s);
        gld16(g + (size_t)8 * lda, s + 8 * 64);
    };
    auto stageB = [&](int buf, int half, int k0) {
        const unsigned short* g = gB + (size_t)(half * 128) * ldb + k0;
        unsigned short* s = &Bs[buf][half][(w * 16) * 64];
        gld16(g, s);
        gld16(g + (size_t)8 * ldb, s + 8 * 64);
    };

    stageA(0, 0, 0); stageA(0, 1, 0);
    stageB(0, 0, 0); stageB(0, 1, 0);
    int kp = (NB > 1) ? 64 : 0;
    stageB(1, 0, kp); stageB(1, 1, kp); stageA(1, 0, kp);
    WAIT_VM6();
    __builtin_amdgcn_s_barrier();

    bf16x8 aF0[2][4], aF1[2][4], bF[2][4];  // [kchunk][frag]

    for (int j = 0; j < NB; j++) {
        int b = j & 1;
        int k1 = ((j + 1 < NB) ? (j + 1) : (NB - 1)) << 6;
        int k2 = ((j + 2 < NB) ? (j + 2) : (NB - 1)) << 6;
        const unsigned short* Ah = &As[b][wmh][0];
        const unsigned short* Bh = &Bs[b][wnh][0];

        // ---- P1 ----
#pragma unroll
        for (int kc = 0; kc < 2; kc++) {
#pragma unroll
            for (int f = 0; f < 4; f++)
                bF[kc][f] = *(const bf16x8*)(Bh + (bnl + f * 16 + lr) * 64 + ((kc * 32 + c0) ^ rx));
#pragma unroll
            for (int f = 0; f < 4; f++)
                aF0[kc][f] = *(const bf16x8*)(Ah + (f * 16 + lr) * 64 + ((kc * 32 + c0) ^ rx));
        }
        stageA(b ^ 1, 1, k1);
        __builtin_amdgcn_s_barrier();
        __builtin_amdgcn_s_setprio(1);
#pragma unroll
        for (int kc = 0; kc < 2; kc++)
#pragma unroll
            for (int i = 0; i < 4; i++)
#pragma unroll
                for (int jn = 0; jn < 2; jn++)
                    acc[i][jn] = __builtin_amdgcn_mfma_f32_16x16x32_bf16(
                        aF0[kc][i], bF[kc][jn], acc[i][jn], 0, 0, 0);
        __builtin_amdgcn_s_setprio(0);
        __builtin_amdgcn_s_barrier();

        // ---- P2 ----
#pragma unroll
        for (int kc = 0; kc < 2; kc++)
#pragma unroll
            for (int f = 0; f < 4; f++)
                aF1[kc][f] = *(const bf16x8*)(Ah + (64 + f * 16 + lr) * 64 + ((kc * 32 + c0) ^ rx));
        stageB(b, 0, k2);
        __builtin_amdgcn_s_barrier();
        __builtin_amdgcn_s_setprio(1);
#pragma unroll
        for (int kc = 0; kc < 2; kc++)
#pragma unroll
            for (int i = 0; i < 4; i++)
#pragma unroll
                for (int jn = 0; jn < 2; jn++)
                    acc[4 + i][jn] = __builtin_amdgcn_mfma_f32_16x16x32_bf16(
                        aF1[kc][i], bF[kc][jn], acc[4 + i][jn], 0, 0, 0);
        __builtin_amdgcn_s_setprio(0);
        __builtin_amdgcn_s_barrier();

        // ---- P3 ----
        stageB(b, 1, k2);
        __builtin_amdgcn_s_barrier();
        __builtin_amdgcn_s_setprio(1);
#pragma unroll
        for (int kc = 0; kc < 2; kc++)
#pragma unroll
            for (int i = 0; i < 4; i++)
#pragma unroll
                for (int jn = 0; jn < 2; jn++)
                    acc[4 + i][2 + jn] = __builtin_amdgcn_mfma_f32_16x16x32_bf16(
                        aF1[kc][i], bF[kc][2 + jn], acc[4 + i][2 + jn], 0, 0, 0);
        __builtin_amdgcn_s_setprio(0);
        __builtin_amdgcn_s_barrier();

        // ---- P4 ----
        stageA(b, 0, k2);
        WAIT_VM6();
        __builtin_amdgcn_s_barrier();
        __builtin_amdgcn_s_setprio(1);
#pragma unroll
        for (int kc = 0; kc < 2; kc++)
#pragma unroll
            for (int i = 0; i < 4; i++)
#pragma unroll
                for (int jn = 0; jn < 2; jn++)
                    acc[i][2 + jn] = __builtin_amdgcn_mfma_f32_16x16x32_bf16(
                        aF0[kc][i], bF[kc][2 + jn], acc[i][2 + jn], 0, 0, 0);
        __builtin_amdgcn_s_setprio(0);
        __builtin_amdgcn_s_barrier();
    }
    WAIT_VM0();

#pragma unroll
    for (int i = 0; i < 8; i++) {
        int mbase = bm * 256 + wmh * 128 + i * 16 + lq * 4;
#pragma unroll
        for (int jn = 0; jn < 4; jn++) {
            int n = bn * 256 + (w & 3) * 64 + jn * 16 + lr;
            if (EPI == 6) {
                if (n < 2048) {  // Q,K region: row-major into C
#pragma unroll
                    for (int r = 0; r < 4; r++)
                        Cb[(long long)(mbase + r) * ldc + n] = f2bf(acc[i][jn][r]);
                } else {         // V region: transposed 8B store into VT
                    unsigned short* VTp = (unsigned short*)(size_t)res;
                    ushort4 o;
                    o.x = f2bf(acc[i][jn][0]);
                    o.y = f2bf(acc[i][jn][1]);
                    o.z = f2bf(acc[i][jn][2]);
                    o.w = f2bf(acc[i][jn][3]);
                    size_t voff = ((size_t)(mbase >> 11) << 21)      // batch * D*S
                                + (size_t)(n - 2048) * S_ + (mbase & 2047);
                    *(ushort4*)(VTp + voff) = o;
                }
            } else {
#pragma unroll
                for (int r = 0; r < 4; r++) {
                    int m = mbase + r;
                    float v = acc[i][jn][r];
                    long long idx = coff + (long long)m * ldc + n;
                    if (EPI == 0) {
                        Cb[idx] = f2bf(v);
                    } else if (EPI == 1) {
                        Cb[idx] = f2bf(v * scale);
                    } else if (EPI == 2) {
                        Cf[idx] = v + res[idx];
                    } else if (EPI == 3) {
                        float u = v + bias[n];
                        Cb[idx] = f2bf(u > 0.f ? u : 0.f);
                    } else {  // EPI == 4
                        Cf[idx] = v + bias[n] + res[idx];
                    }
                }
            }
        }
    }
}

extern "C" void kernel_launch(void* const* d_in, const int* in_sizes, int n_in,
                              void* d_out, int out_size, void* d_ws, size_t ws_size,
                              hipStream_t stream) {
    const float* x      = (const float*)d_in[0];
    const float* Qw     = (const float*)d_in[1];
    const float* Kw     = (const float*)d_in[2];
    const float* Vw     = (const float*)d_in[3];
    const float* w1     = (const float*)d_in[4];
    const float* b1     = (const float*)d_in[5];
    const float* w2     = (const float*)d_in[6];
    const float* b2     = (const float*)d_in[7];
    const float* gamma1 = (const float*)d_in[8];
    const float* beta1  = (const float*)d_in[9];
    const float* gamma2 = (const float*)d_in[10];
    const float* beta2  = (const float*)d_in[11];
    float* out = (float*)d_out;

    char* ws = (char*)d_ws;
    size_t off = 0;
    auto alloc = [&](size_t bytes) -> void* {
        void* p = ws + off;
        off += (bytes + 255) & ~(size_t)255;
        return p;
    };
    const size_t MN = (size_t)B_ * S_ * D_;  // 8.4M elems
    unsigned short* xn     = (unsigned short*)alloc(MN * 2);                     // 16.8MB
    unsigned short* scoreP = (unsigned short*)alloc((size_t)B_ * S_ * S_ * 2);   // 33.6MB, scores->P in place
    unsigned short* qkv    = (unsigned short*)alloc((size_t)B_ * S_ * 3072 * 2); // 50.3MB interleaved Q|K|(V unused)
    unsigned short* VT     = (unsigned short*)alloc(MN * 2);                     // 16.8MB
    unsigned short* QKVwT  = (unsigned short*)alloc((size_t)3 * D_ * D_ * 2);    // 6.3MB
    unsigned short* w1T    = (unsigned short*)alloc((size_t)D_ * F_ * 2);        // 8.4MB
    unsigned short* w2T    = (unsigned short*)alloc((size_t)F_ * D_ * 2);        // 8.4MB
    // mid (8192 x 4096 bf16 = 67,108,864 B) overlays qkv+VT (dead after PV).
    unsigned short* mid = qkv;

    dim3 tb(32, 8);
    // weight conversion (transposed so all GEMMs take Bt = N x K)
    k_transpose_w3<<<dim3(D_ / 32, D_ / 32, 3), tb, 0, stream>>>(Qw, Kw, Vw, QKVwT);
    k_transpose_f32_bf16<<<dim3(F_ / 32, D_ / 32), tb, 0, stream>>>(w1, w1T, D_, F_);
    k_transpose_f32_bf16<<<dim3(D_ / 32, F_ / 32), tb, 0, stream>>>(w2, w2T, F_, D_);

    // LN1
    k_layernorm<<<B_ * S_, 256, 0, stream>>>(x, gamma1, beta1, xn);

    // fused QKV projection: M = 8192, N = 3072, K = 1024. Q,K -> qkv row-major
    // (ldc 3072); V -> VT directly transposed (EPI=6, VT via res). The separate
    // V-transpose pass (34 MB) is eliminated.
    const int Mtok = B_ * S_;
    k_gemm256<6><<<dim3(3072 / 256, Mtok / 256), 512, 0, stream>>>(
        xn, QKVwT, qkv, nullptr, (const float*)VT, D_, D_, D_, 3072, 0, 0, 0, 1.f, 0);

    // scores = Q @ K^T / 32 (batched, bf16 out), upper-tri blocks skipped
    // (k_gemm256: round-7 A/B showed legacy here is 3 us WORSE — short-K
    // batched shapes don't hit the 1-blk/CU collapse)
    k_gemm256<1><<<dim3(S_ / 256, S_ / 256, B_), 512, 0, stream>>>(
        qkv, qkv + 1024, scoreP, nullptr, nullptr, D_, 3072, 3072, S_,
        (long long)S_ * 3072, (long long)S_ * 3072, (long long)S_ * S_, 0.03125f, 0);

    // causal softmax in place -> P (bf16), truncated to lower-tri + pad
    k_softmax<<<B_ * S_, 256, 0, stream>>>(scoreP);

    // attn = P @ V + x -> out (fp32); K-loop truncated at diagonal (mult of 64)
    k_gemm_bt<2><<<dim3(D_ / 128, S_ / 128, B_), 256, 0, stream>>>(
        scoreP, VT, out, nullptr, x, S_, S_, S_, D_,
        (long long)S_ * S_, (long long)D_ * S_, (long long)S_ * D_, 1.f, 1, 2);

    // LN2 on out -> xn (h)
    k_layernorm<<<B_ * S_, 256, 0, stream>>>(out, gamma2, beta2, xn);

    // mid = relu(h @ w1 + b1) (bf16), 256^2 4-phase: grid 16x32 = 512 blocks
    k_gemm256<3><<<dim3(F_ / 256, Mtok / 256), 512, 0, stream>>>(
        xn, w1T, mid, b1, nullptr, D_, D_, D_, F_, 0, 0, 0, 1.f, 0);

    // out = out + mid @ w2 + b2 (legacy 128^2, 2 blocks/CU — best known for
    // this shape; rounds 3-5 A/B'd three deeper 1-block/CU schedules, all lost)
    k_gemm_bt<4><<<dim3(D_ / 128, Mtok / 128), 256, 0, stream>>>(
        mid, w2T, out, b2, out, F_, F_, F_, D_, 0, 0, 0, 1.f, 0, 2);
}

// Round 9
// 462.551 us; speedup vs baseline: 1.0286x; 1.0085x over previous
//
#include <hip/hip_runtime.h>
#include <hip/hip_bf16.h>

#define B_ 4
#define S_ 2048
#define D_ 1024
#define F_ 4096

typedef short bf16x8 __attribute__((ext_vector_type(8)));
typedef float f32x4 __attribute__((ext_vector_type(4)));

static __device__ __forceinline__ unsigned short f2bf(float f) {
    union { float f; unsigned int u; } v; v.f = f;
    unsigned int u = v.u + 0x7FFF + ((v.u >> 16) & 1);  // RNE
    return (unsigned short)(u >> 16);
}
static __device__ __forceinline__ float bf2f(unsigned short u) {
    union { unsigned int u; float f; } v; v.u = ((unsigned int)u) << 16;
    return v.f;
}

// async global->LDS, 16B per lane. LDS dest is wave-uniform base + lane*16.
typedef const __attribute__((address_space(1))) unsigned int* gp_t;
typedef __attribute__((address_space(3))) unsigned int* lp_t;
static __device__ __forceinline__ void gld16(const unsigned short* g, unsigned short* l) {
    __builtin_amdgcn_global_load_lds((gp_t)g, (lp_t)l, 16, 0, 0);
}

// s_waitcnt with selected counters masked off (gfx9 encoding:
// vmcnt[3:0]|[15:14], expcnt[6:4], lgkmcnt[11:8])
#define WAIT_VM8()   __builtin_amdgcn_s_waitcnt(0x0F78)
#define WAIT_VM6()   __builtin_amdgcn_s_waitcnt(0x0F76)
#define WAIT_VM0()   __builtin_amdgcn_s_waitcnt(0x0F70)
#define WAIT_LGKM0() __builtin_amdgcn_s_waitcnt(0xC07F)  // lgkmcnt(0) only

// ---------------- transpose fp32 (R x C) -> bf16 (C x R) ----------------
__global__ __launch_bounds__(256) void k_transpose_f32_bf16(
    const float* __restrict__ in, unsigned short* __restrict__ out, int R, int C) {
    __shared__ float t[32][33];
    int c0 = blockIdx.x * 32, r0 = blockIdx.y * 32;
    int x = threadIdx.x, y = threadIdx.y;  // 32 x 8
#pragma unroll
    for (int i = 0; i < 4; i++)
        t[y + 8 * i][x] = in[(size_t)(r0 + y + 8 * i) * C + c0 + x];
    __syncthreads();
#pragma unroll
    for (int i = 0; i < 4; i++)
        out[(size_t)(c0 + y + 8 * i) * R + r0 + x] = f2bf(t[x][y + 8 * i]);
}

// QKV weight transposes fused: z picks source, writes QKVwT + z*D*D (each D x D)
__global__ __launch_bounds__(256) void k_transpose_w3(
    const float* __restrict__ Qw, const float* __restrict__ Kw, const float* __restrict__ Vw,
    unsigned short* __restrict__ out) {
    __shared__ float t[32][33];
    int z = blockIdx.z;
    const float* in = (z == 0) ? Qw : (z == 1) ? Kw : Vw;
    out += (size_t)z * D_ * D_;
    int c0 = blockIdx.x * 32, r0 = blockIdx.y * 32;
    int x = threadIdx.x, y = threadIdx.y;
#pragma unroll
    for (int i = 0; i < 4; i++)
        t[y + 8 * i][x] = in[(size_t)(r0 + y + 8 * i) * D_ + c0 + x];
    __syncthreads();
#pragma unroll
    for (int i = 0; i < 4; i++)
        out[(size_t)(c0 + y + 8 * i) * D_ + r0 + x] = f2bf(t[x][y + 8 * i]);
}

// ---------------- layernorm: fp32 row (D_) -> bf16 row ----------------
__global__ __launch_bounds__(256) void k_layernorm(
    const float* __restrict__ x, const float* __restrict__ gamma,
    const float* __restrict__ beta, unsigned short* __restrict__ out) {
    int row = blockIdx.x;
    int t = threadIdx.x;
    const float* xr = x + (size_t)row * D_;
    float4 v = ((const float4*)xr)[t];
    float s = v.x + v.y + v.z + v.w;
    float q = v.x * v.x + v.y * v.y + v.z * v.z + v.w * v.w;
#pragma unroll
    for (int off = 32; off; off >>= 1) {
        s += __shfl_down(s, off);
        q += __shfl_down(q, off);
    }
    __shared__ float ls[4], lq[4];
    int wv = t >> 6;
    if ((t & 63) == 0) { ls[wv] = s; lq[wv] = q; }
    __syncthreads();
    if (t == 0) {
        float S = ls[0] + ls[1] + ls[2] + ls[3];
        float Q = lq[0] + lq[1] + lq[2] + lq[3];
        float mean = S * (1.0f / D_);
        float var = Q * (1.0f / D_) - mean * mean;
        ls[0] = mean; lq[0] = rsqrtf(var + 1e-5f);
    }
    __syncthreads();
    float mean = ls[0], rstd = lq[0];
    float4 g = ((const float4*)gamma)[t];
    float4 b = ((const float4*)beta)[t];
    ushort4 o;
    o.x = f2bf(g.x * (v.x - mean) * rstd + b.x);
    o.y = f2bf(g.y * (v.y - mean) * rstd + b.y);
    o.z = f2bf(g.z * (v.z - mean) * rstd + b.z);
    o.w = f2bf(g.w * (v.w - mean) * rstd + b.w);
    ((ushort4*)(out + (size_t)row * D_))[t] = o;
}

// ---------------- causal softmax, in-place on bf16 scores rows ----------------
// Vectorized 16B/lane (bf16x8); thread t owns elems 8t..8t+7.
// Causal truncation: read only j < valid; write only j < roundup(valid,128).
__global__ __launch_bounds__(256) void k_softmax(unsigned short* __restrict__ sp) {
    int r = blockIdx.x;          // global row in [0, B_*S_)
    int i = r & (S_ - 1);        // query index within batch
    unsigned short* row = sp + (size_t)r * S_;
    int t = threadIdx.x;
    int valid = i + 1;
    int wlim = (valid + 127) & ~127;  // multiple of 128 (and of 8)
    bf16x8 v8 = {};
    if (t * 8 < valid) v8 = *(const bf16x8*)(row + t * 8);
    float vals[8];
    float mx = -1e30f;
#pragma unroll
    for (int k = 0; k < 8; k++) {
        int j = t * 8 + k;
        vals[k] = (j < valid) ? bf2f((unsigned short)v8[k]) : -1e30f;
        mx = fmaxf(mx, vals[k]);
    }
#pragma unroll
    for (int off = 32; off; off >>= 1) mx = fmaxf(mx, __shfl_xor(mx, off));
    __shared__ float red[4];
    if ((t & 63) == 0) red[t >> 6] = mx;
    __syncthreads();
    mx = fmaxf(fmaxf(red[0], red[1]), fmaxf(red[2], red[3]));
    __syncthreads();
    float e[8];
    float sum = 0.f;
#pragma unroll
    for (int k = 0; k < 8; k++) {
        int j = t * 8 + k;
        e[k] = (j < valid) ? __expf(vals[k] - mx) : 0.f;
        sum += e[k];
    }
#pragma unroll
    for (int off = 32; off; off >>= 1) sum += __shfl_xor(sum, off);
    if ((t & 63) == 0) red[t >> 6] = sum;
    __syncthreads();
    sum = red[0] + red[1] + red[2] + red[3];
    float inv = 1.0f / sum;
    if (t * 8 < wlim) {
        bf16x8 o8;
#pragma unroll
        for (int k = 0; k < 8; k++) o8[k] = (short)f2bf(e[k] * inv);
        *(bf16x8*)(row + t * 8) = o8;
    }
}

// ---------------- GEMM (legacy 128x128, 2-phase counted-vmcnt) ----------------
// Used for PV (klimit) and FFN2 (N=1024). 64KB LDS -> 2 blocks/CU: cross-block
// TLP fills barrier gaps — empirically beats every 1-block/CU deep schedule
// tried for long-K skinny shapes (rounds 3-5).
template <int EPI>
__global__ __launch_bounds__(256) void k_gemm_bt(
    const unsigned short* __restrict__ A, const unsigned short* __restrict__ Bt,
    void* __restrict__ Cv, const float* __restrict__ bias, const float* __restrict__ res,
    int K, int lda, int ldb, int ldc,
    long long sA, long long sB, long long sC, float scale, int klimit, int swz) {
    int bn, bm, z;
    if (swz > 0) {
        int GN = gridDim.x, GM = gridDim.y;
        int L = blockIdx.x + GN * (blockIdx.y + GM * blockIdx.z);
        int rows = gridDim.y * gridDim.z;
        int xcd = L & 7;
        int s = L >> 3;
        int bng = GN / swz;
        int rpg = rows * swz / 8;
        int xg = xcd % swz, yg = xcd / swz;
        int bnl = s % bng;
        int rl = s / bng;
        int row = yg * rpg + rl;
        bn = xg * bng + bnl;
        bm = row % GM;
        z = row / GM;
    } else {
        bn = blockIdx.x; bm = blockIdx.y; z = blockIdx.z;
    }
    if (EPI == 1 && bn > bm) return;
    A += (long long)z * sA;
    Bt += (long long)z * sB;
    long long coff = (long long)z * sC;
    float* Cf = (float*)Cv;
    unsigned short* Cb = (unsigned short*)Cv;

    __shared__ unsigned short As[2][2][128 * 32];
    __shared__ unsigned short Bs[2][2][128 * 32];

    int t = threadIdx.x;
    int l = t & 63, w = t >> 6;
    int wm = (w & 1) * 64, wn = (w >> 1) * 64;
    int lr = l & 15, lq = l >> 4;

    f32x4 acc[4][4];
#pragma unroll
    for (int i = 0; i < 4; i++)
#pragma unroll
        for (int j = 0; j < 4; j++) acc[i][j] = (f32x4){0.f, 0.f, 0.f, 0.f};

    int kend = K;
    if (klimit) { int ke = (bm + 1) * 128; kend = ke < K ? ke : K; }

    int sr = l >> 2;
    int sc = (l & 3) * 8;
    const unsigned short* gA0 = A + (size_t)(bm * 128 + w * 32 + sr) * lda + sc;
    const unsigned short* gA1 = gA0 + (size_t)16 * lda;
    const unsigned short* gB0 = Bt + (size_t)(bn * 128 + w * 32 + sr) * ldb + sc;
    const unsigned short* gB1 = gB0 + (size_t)16 * ldb;

    auto stage = [&](int buf, int k0) {
#pragma unroll
        for (int kc = 0; kc < 2; kc++) {
            int kk = k0 + kc * 32;
            gld16(gA0 + kk, &As[buf][kc][(w * 32) * 32]);
            gld16(gA1 + kk, &As[buf][kc][(w * 32 + 16) * 32]);
            gld16(gB0 + kk, &Bs[buf][kc][(w * 32) * 32]);
            gld16(gB1 + kk, &Bs[buf][kc][(w * 32 + 16) * 32]);
        }
    };

    int NB = kend >> 6;
    stage(0, 0);
    for (int it = 0; it < NB; it++) {
        int cur = it & 1;
        if (it + 1 < NB) {
            stage(1 - cur, (it + 1) * 64);
            WAIT_VM8();
        } else {
            WAIT_VM0();
        }
        __builtin_amdgcn_s_barrier();
#pragma unroll
        for (int kc = 0; kc < 2; kc++) {
            bf16x8 af[4], bf[4];
#pragma unroll
            for (int i = 0; i < 4; i++)
                af[i] = *(const bf16x8*)(&As[cur][kc][(wm + i * 16 + lr) * 32 + lq * 8]);
#pragma unroll
            for (int j = 0; j < 4; j++)
                bf[j] = *(const bf16x8*)(&Bs[cur][kc][(wn + j * 16 + lr) * 32 + lq * 8]);
#pragma unroll
            for (int i = 0; i < 4; i++)
#pragma unroll
                for (int j = 0; j < 4; j++)
                    acc[i][j] = __builtin_amdgcn_mfma_f32_16x16x32_bf16(af[i], bf[j], acc[i][j], 0, 0, 0);
        }
        __builtin_amdgcn_s_barrier();
    }

#pragma unroll
    for (int i = 0; i < 4; i++) {
        int mbase = bm * 128 + wm + i * 16 + lq * 4;
#pragma unroll
        for (int j = 0; j < 4; j++) {
            int n = bn * 128 + wn + j * 16 + lr;
#pragma unroll
            for (int r = 0; r < 4; r++) {
                int m = mbase + r;
                float v = acc[i][j][r];
                long long idx = coff + (long long)m * ldc + n;
                if (EPI == 0) {
                    Cb[idx] = f2bf(v);
                } else if (EPI == 1) {
                    Cb[idx] = f2bf(v * scale);
                } else if (EPI == 2) {
                    Cf[idx] = v + res[idx];
                } else if (EPI == 3) {
                    float u = v + bias[n];
                    Cb[idx] = f2bf(u > 0.f ? u : 0.f);
                } else {
                    Cf[idx] = v + bias[n] + res[idx];
                }
            }
        }
    }
}

// ---------------- GEMM 256x256, 8-wave, BK=64, 4-phase/K-tile ----------------
// (verified round 2) T2 3-bit XOR swizzle both-sides, T3+T4 counted vmcnt(6),
// T5 setprio. Used for QKV / scores / FFN1.
// EPI=6: fused QKV epilogue. Block-uniform split at bn=8 (n=2048 boundary):
//   bn<8 : Q,K tile -> row-major into C (ldc 3072), as EPI=0.
//   bn>=8: V tile -> VT via PER-WAVE LDS TRANSPOSE (round-9 fix): the direct
//          8B scatter (round 8) made 64-lane stores span 16 S_-strided lines
//          -> QKV 104.7us @ 19.6% MfmaUtil. Now: wave w transposes its
//          64n x 128m sub-tile in its own 16KB LDS slice (XOR-swizzled),
//          then stores coalesced 256B/16-lane rows. vm0+barrier before LDS
//          reuse (other waves' in-flight gld16 target rows in my slice).
template <int EPI>
__global__ __launch_bounds__(512, 2) void k_gemm256(
    const unsigned short* __restrict__ A, const unsigned short* __restrict__ Bt,
    void* __restrict__ Cv, const float* __restrict__ bias, const float* __restrict__ res,
    int K, int lda, int ldb, int ldc,
    long long sA, long long sB, long long sC, float scale, int klimit) {
    int bn = blockIdx.x, bm = blockIdx.y, z = blockIdx.z;
    if (EPI == 1 && bn > bm) return;  // fully-masked causal block
    A += (long long)z * sA;
    Bt += (long long)z * sB;
    long long coff = (long long)z * sC;
    float* Cf = (float*)Cv;
    unsigned short* Cb = (unsigned short*)Cv;

    __shared__ unsigned short As[2][2][128 * 64];
    __shared__ unsigned short Bs[2][2][128 * 64];

    int t = threadIdx.x;
    int l = t & 63, w = t >> 6;       // lane, wave 0..7 (2M x 4N)
    int wmh = w >> 2;                 // which A half this wave reads
    int wnh = (w >> 1) & 1;           // which B half this wave reads
    int bnl = (w & 1) * 64;           // row base within that B half
    int lr = l & 15, lq = l >> 4;
    int rx = (lr & 7) << 3;           // read-side swizzle XOR (elems)
    int c0 = lq * 8;                  // un-swizzled k-subcolumn (elems)

    f32x4 acc[8][4];
#pragma unroll
    for (int i = 0; i < 8; i++)
#pragma unroll
        for (int j = 0; j < 4; j++) acc[i][j] = (f32x4){0.f, 0.f, 0.f, 0.f};

    int kend = K;
    if (klimit) { int ke = (bm + 1) * 256; kend = ke < K ? ke : K; }
    int NB = kend >> 6;

    int grow = l >> 3;
    int gcol = ((l & 7) * 8) ^ (((l >> 3) & 7) << 3);
    const unsigned short* gA = A + (size_t)(bm * 256 + w * 16 + grow) * lda + gcol;
    const unsigned short* gB = Bt + (size_t)(bn * 256 + w * 16 + grow) * ldb + gcol;

    auto stageA = [&](int buf, int half, int k0) {
        const unsigned short* g = gA + (size_t)(half * 128) * lda + k0;
        unsigned short* s = &As[buf][half][(w * 16) * 64];
        gld16(g, s);
        gld16(g + (size_t)8 * lda, s + 8 * 64);
    };
    auto stageB = [&](int buf, int half, int k0) {
        const unsigned short* g = gB + (size_t)(half * 128) * ldb + k0;
        unsigned short* s = &Bs[buf][half][(w * 16) * 64];
        gld16(g, s);
        gld16(g + (size_t)8 * ldb, s + 8 * 64);
    };

    stageA(0, 0, 0); stageA(0, 1, 0);
    stageB(0, 0, 0); stageB(0, 1, 0);
    int kp = (NB > 1) ? 64 : 0;
    stageB(1, 0, kp); stageB(1, 1, kp); stageA(1, 0, kp);
    WAIT_VM6();
    __builtin_amdgcn_s_barrier();

    bf16x8 aF0[2][4], aF1[2][4], bF[2][4];  // [kchunk][frag]

    for (int j = 0; j < NB; j++) {
        int b = j & 1;
        int k1 = ((j + 1 < NB) ? (j + 1) : (NB - 1)) << 6;
        int k2 = ((j + 2 < NB) ? (j + 2) : (NB - 1)) << 6;
        const unsigned short* Ah = &As[b][wmh][0];
        const unsigned short* Bh = &Bs[b][wnh][0];

        // ---- P1 ----
#pragma unroll
        for (int kc = 0; kc < 2; kc++) {
#pragma unroll
            for (int f = 0; f < 4; f++)
                bF[kc][f] = *(const bf16x8*)(Bh + (bnl + f * 16 + lr) * 64 + ((kc * 32 + c0) ^ rx));
#pragma unroll
            for (int f = 0; f < 4; f++)
                aF0[kc][f] = *(const bf16x8*)(Ah + (f * 16 + lr) * 64 + ((kc * 32 + c0) ^ rx));
        }
        stageA(b ^ 1, 1, k1);
        __builtin_amdgcn_s_barrier();
        __builtin_amdgcn_s_setprio(1);
#pragma unroll
        for (int kc = 0; kc < 2; kc++)
#pragma unroll
            for (int i = 0; i < 4; i++)
#pragma unroll
                for (int jn = 0; jn < 2; jn++)
                    acc[i][jn] = __builtin_amdgcn_mfma_f32_16x16x32_bf16(
                        aF0[kc][i], bF[kc][jn], acc[i][jn], 0, 0, 0);
        __builtin_amdgcn_s_setprio(0);
        __builtin_amdgcn_s_barrier();

        // ---- P2 ----
#pragma unroll
        for (int kc = 0; kc < 2; kc++)
#pragma unroll
            for (int f = 0; f < 4; f++)
                aF1[kc][f] = *(const bf16x8*)(Ah + (64 + f * 16 + lr) * 64 + ((kc * 32 + c0) ^ rx));
        stageB(b, 0, k2);
        __builtin_amdgcn_s_barrier();
        __builtin_amdgcn_s_setprio(1);
#pragma unroll
        for (int kc = 0; kc < 2; kc++)
#pragma unroll
            for (int i = 0; i < 4; i++)
#pragma unroll
                for (int jn = 0; jn < 2; jn++)
                    acc[4 + i][jn] = __builtin_amdgcn_mfma_f32_16x16x32_bf16(
                        aF1[kc][i], bF[kc][jn], acc[4 + i][jn], 0, 0, 0);
        __builtin_amdgcn_s_setprio(0);
        __builtin_amdgcn_s_barrier();

        // ---- P3 ----
        stageB(b, 1, k2);
        __builtin_amdgcn_s_barrier();
        __builtin_amdgcn_s_setprio(1);
#pragma unroll
        for (int kc = 0; kc < 2; kc++)
#pragma unroll
            for (int i = 0; i < 4; i++)
#pragma unroll
                for (int jn = 0; jn < 2; jn++)
                    acc[4 + i][2 + jn] = __builtin_amdgcn_mfma_f32_16x16x32_bf16(
                        aF1[kc][i], bF[kc][2 + jn], acc[4 + i][2 + jn], 0, 0, 0);
        __builtin_amdgcn_s_setprio(0);
        __builtin_amdgcn_s_barrier();

        // ---- P4 ----
        stageA(b, 0, k2);
        WAIT_VM6();
        __builtin_amdgcn_s_barrier();
        __builtin_amdgcn_s_setprio(1);
#pragma unroll
        for (int kc = 0; kc < 2; kc++)
#pragma unroll
            for (int i = 0; i < 4; i++)
#pragma unroll
                for (int jn = 0; jn < 2; jn++)
                    acc[i][2 + jn] = __builtin_amdgcn_mfma_f32_16x16x32_bf16(
                        aF0[kc][i], bF[kc][2 + jn], acc[i][2 + jn], 0, 0, 0);
        __builtin_amdgcn_s_setprio(0);
        __builtin_amdgcn_s_barrier();
    }
    WAIT_VM0();

    if (EPI == 6 && bn >= 8) {
        // ---- V block: per-wave LDS transpose -> coalesced VT stores ----
        __builtin_amdgcn_s_barrier();  // all waves drained their gld16 (vm0 above)
        unsigned short* T = (w < 4) ? (unsigned short*)As + (size_t)w * 8192
                                    : (unsigned short*)Bs + (size_t)(w - 4) * 8192;
        // write: wave's 64n x 128m sub-tile, [n][m] layout, 8-elem-slot XOR swz
#pragma unroll
        for (int i = 0; i < 8; i++)
#pragma unroll
            for (int jn = 0; jn < 4; jn++) {
                int nl = jn * 16 + lr;          // 0..63
                int ml = i * 16 + lq * 4;       // 0..127, 4-aligned
                ushort4 o;
                o.x = f2bf(acc[i][jn][0]);
                o.y = f2bf(acc[i][jn][1]);
                o.z = f2bf(acc[i][jn][2]);
                o.w = f2bf(acc[i][jn][3]);
                *(ushort4*)&T[nl * 128 + (((ml & ~7) ^ ((nl & 7) << 3)) | (ml & 7))] = o;
            }
        WAIT_LGKM0();
        __builtin_amdgcn_s_barrier();
        // read rows + coalesced store: 16 passes, 4 rows x 16 lanes x 16B each
        unsigned short* VTp = (unsigned short*)(size_t)res;
        int batch = (bm * 256) >> 11;
        size_t mb0 = (size_t)((bm * 256) & 2047) + (size_t)wmh * 128;
        size_t nb0 = (size_t)(bn * 256 - 2048 + (w & 3) * 64);
        size_t vbase = (size_t)batch * D_ * S_ + mb0;
#pragma unroll
        for (int p = 0; p < 16; p++) {
            int nl = p * 4 + (l >> 4);
            int mo = (l & 15) * 8;
            bf16x8 v = *(const bf16x8*)&T[nl * 128 + (mo ^ ((nl & 7) << 3))];
            *(bf16x8*)(VTp + vbase + (nb0 + nl) * S_ + mo) = v;
        }
    } else {
#pragma unroll
        for (int i = 0; i < 8; i++) {
            int mbase = bm * 256 + wmh * 128 + i * 16 + lq * 4;
#pragma unroll
            for (int jn = 0; jn < 4; jn++) {
                int n = bn * 256 + (w & 3) * 64 + jn * 16 + lr;
#pragma unroll
                for (int r = 0; r < 4; r++) {
                    int m = mbase + r;
                    float v = acc[i][jn][r];
                    long long idx = coff + (long long)m * ldc + n;
                    if (EPI == 0 || EPI == 6) {
                        Cb[idx] = f2bf(v);
                    } else if (EPI == 1) {
                        Cb[idx] = f2bf(v * scale);
                    } else if (EPI == 2) {
                        Cf[idx] = v + res[idx];
                    } else if (EPI == 3) {
                        float u = v + bias[n];
                        Cb[idx] = f2bf(u > 0.f ? u : 0.f);
                    } else {  // EPI == 4
                        Cf[idx] = v + bias[n] + res[idx];
                    }
                }
            }
        }
    }
}

extern "C" void kernel_launch(void* const* d_in, const int* in_sizes, int n_in,
                              void* d_out, int out_size, void* d_ws, size_t ws_size,
                              hipStream_t stream) {
    const float* x      = (const float*)d_in[0];
    const float* Qw     = (const float*)d_in[1];
    const float* Kw     = (const float*)d_in[2];
    const float* Vw     = (const float*)d_in[3];
    const float* w1     = (const float*)d_in[4];
    const float* b1     = (const float*)d_in[5];
    const float* w2     = (const float*)d_in[6];
    const float* b2     = (const float*)d_in[7];
    const float* gamma1 = (const float*)d_in[8];
    const float* beta1  = (const float*)d_in[9];
    const float* gamma2 = (const float*)d_in[10];
    const float* beta2  = (const float*)d_in[11];
    float* out = (float*)d_out;

    char* ws = (char*)d_ws;
    size_t off = 0;
    auto alloc = [&](size_t bytes) -> void* {
        void* p = ws + off;
        off += (bytes + 255) & ~(size_t)255;
        return p;
    };
    const size_t MN = (size_t)B_ * S_ * D_;  // 8.4M elems
    unsigned short* xn     = (unsigned short*)alloc(MN * 2);                     // 16.8MB
    unsigned short* scoreP = (unsigned short*)alloc((size_t)B_ * S_ * S_ * 2);   // 33.6MB, scores->P in place
    unsigned short* qkv    = (unsigned short*)alloc((size_t)B_ * S_ * 3072 * 2); // 50.3MB interleaved Q|K|(V unused)
    unsigned short* VT     = (unsigned short*)alloc(MN * 2);                     // 16.8MB
    unsigned short* QKVwT  = (unsigned short*)alloc((size_t)3 * D_ * D_ * 2);    // 6.3MB
    unsigned short* w1T    = (unsigned short*)alloc((size_t)D_ * F_ * 2);        // 8.4MB
    unsigned short* w2T    = (unsigned short*)alloc((size_t)F_ * D_ * 2);        // 8.4MB
    // mid (8192 x 4096 bf16 = 67,108,864 B) overlays qkv+VT (dead after PV).
    unsigned short* mid = qkv;

    dim3 tb(32, 8);
    // weight conversion (transposed so all GEMMs take Bt = N x K)
    k_transpose_w3<<<dim3(D_ / 32, D_ / 32, 3), tb, 0, stream>>>(Qw, Kw, Vw, QKVwT);
    k_transpose_f32_bf16<<<dim3(F_ / 32, D_ / 32), tb, 0, stream>>>(w1, w1T, D_, F_);
    k_transpose_f32_bf16<<<dim3(D_ / 32, F_ / 32), tb, 0, stream>>>(w2, w2T, F_, D_);

    // LN1
    k_layernorm<<<B_ * S_, 256, 0, stream>>>(x, gamma1, beta1, xn);

    // fused QKV projection: M = 8192, N = 3072, K = 1024. Q,K -> qkv row-major
    // (ldc 3072); V -> VT directly transposed (EPI=6, VT via res; LDS-transposed
    // coalesced stores). The separate V-transpose pass (34 MB) stays eliminated.
    const int Mtok = B_ * S_;
    k_gemm256<6><<<dim3(3072 / 256, Mtok / 256), 512, 0, stream>>>(
        xn, QKVwT, qkv, nullptr, (const float*)VT, D_, D_, D_, 3072, 0, 0, 0, 1.f, 0);

    // scores = Q @ K^T / 32 (batched, bf16 out), upper-tri blocks skipped
    k_gemm256<1><<<dim3(S_ / 256, S_ / 256, B_), 512, 0, stream>>>(
        qkv, qkv + 1024, scoreP, nullptr, nullptr, D_, 3072, 3072, S_,
        (long long)S_ * 3072, (long long)S_ * 3072, (long long)S_ * S_, 0.03125f, 0);

    // causal softmax in place -> P (bf16), truncated to lower-tri + pad
    k_softmax<<<B_ * S_, 256, 0, stream>>>(scoreP);

    // attn = P @ V + x -> out (fp32); K-loop truncated at diagonal (mult of 64)
    k_gemm_bt<2><<<dim3(D_ / 128, S_ / 128, B_), 256, 0, stream>>>(
        scoreP, VT, out, nullptr, x, S_, S_, S_, D_,
        (long long)S_ * S_, (long long)D_ * S_, (long long)S_ * D_, 1.f, 1, 2);

    // LN2 on out -> xn (h)
    k_layernorm<<<B_ * S_, 256, 0, stream>>>(out, gamma2, beta2, xn);

    // mid = relu(h @ w1 + b1) (bf16), 256^2 4-phase: grid 16x32 = 512 blocks
    k_gemm256<3><<<dim3(F_ / 256, Mtok / 256), 512, 0, stream>>>(
        xn, w1T, mid, b1, nullptr, D_, D_, D_, F_, 0, 0, 0, 1.f, 0);

    // out = out + mid @ w2 + b2 (legacy 128^2, 2 blocks/CU — best known for
    // this shape; rounds 3-5 A/B'd three deeper 1-block/CU schedules, all lost)
    k_gemm_bt<4><<<dim3(D_ / 128, Mtok / 128), 256, 0, stream>>>(
        mid, w2T, out, b2, out, F_, F_, F_, D_, 0, 0, 0, 1.f, 0, 2);
}

// Round 10
// 457.502 us; speedup vs baseline: 1.0400x; 1.0110x over previous
//
#include <hip/hip_runtime.h>
#include <hip/hip_bf16.h>

#define B_ 4
#define S_ 2048
#define D_ 1024
#define F_ 4096

typedef short bf16x8 __attribute__((ext_vector_type(8)));
typedef float f32x4 __attribute__((ext_vector_type(4)));

static __device__ __forceinline__ unsigned short f2bf(float f) {
    union { float f; unsigned int u; } v; v.f = f;
    unsigned int u = v.u + 0x7FFF + ((v.u >> 16) & 1);  // RNE
    return (unsigned short)(u >> 16);
}
static __device__ __forceinline__ float bf2f(unsigned short u) {
    union { unsigned int u; float f; } v; v.u = ((unsigned int)u) << 16;
    return v.f;
}

// async global->LDS, 16B per lane. LDS dest is wave-uniform base + lane*16.
typedef const __attribute__((address_space(1))) unsigned int* gp_t;
typedef __attribute__((address_space(3))) unsigned int* lp_t;
static __device__ __forceinline__ void gld16(const unsigned short* g, unsigned short* l) {
    __builtin_amdgcn_global_load_lds((gp_t)g, (lp_t)l, 16, 0, 0);
}

// s_waitcnt with selected counters masked off (gfx9 encoding:
// vmcnt[3:0]|[15:14], expcnt[6:4], lgkmcnt[11:8])
#define WAIT_VM8()   __builtin_amdgcn_s_waitcnt(0x0F78)
#define WAIT_VM6()   __builtin_amdgcn_s_waitcnt(0x0F76)
#define WAIT_VM0()   __builtin_amdgcn_s_waitcnt(0x0F70)
#define WAIT_LGKM0() __builtin_amdgcn_s_waitcnt(0xC07F)  // lgkmcnt(0) only

// ---------------- fused weight transposes: 5 fp32 matrices -> bf16 ----------
// 1D grid, linear-id decode: [0,3072) QKV weights (3 x 32x32 tile-grids);
// [3072,7168) w1 (D x F -> F x D); [7168,11264) w2 (F x D -> D x F).
// Saves 2 kernel launches vs the previous 3-launch version.
__global__ __launch_bounds__(256) void k_transpose_weights(
    const float* __restrict__ Qw, const float* __restrict__ Kw,
    const float* __restrict__ Vw, const float* __restrict__ w1,
    const float* __restrict__ w2, unsigned short* __restrict__ QKVwT,
    unsigned short* __restrict__ w1T, unsigned short* __restrict__ w2T) {
    __shared__ float t[32][33];
    int id = blockIdx.x;
    const float* in;
    unsigned short* out;
    int R, C, bx, by;
    if (id < 3072) {
        int z = id >> 10, r = id & 1023;
        in = (z == 0) ? Qw : (z == 1) ? Kw : Vw;
        out = QKVwT + (size_t)z * D_ * D_;
        R = D_; C = D_; bx = r & 31; by = r >> 5;
    } else if (id < 7168) {
        int r = id - 3072;
        in = w1; out = w1T; R = D_; C = F_;
        bx = r & 127; by = r >> 7;   // (C/32=128) x (R/32=32)
    } else {
        int r = id - 7168;
        in = w2; out = w2T; R = F_; C = D_;
        bx = r & 31; by = r >> 5;    // (C/32=32) x (R/32=128)
    }
    int c0 = bx * 32, r0 = by * 32;
    int x = threadIdx.x, y = threadIdx.y;  // 32 x 8
#pragma unroll
    for (int i = 0; i < 4; i++)
        t[y + 8 * i][x] = in[(size_t)(r0 + y + 8 * i) * C + c0 + x];
    __syncthreads();
#pragma unroll
    for (int i = 0; i < 4; i++)
        out[(size_t)(c0 + y + 8 * i) * R + r0 + x] = f2bf(t[x][y + 8 * i]);
}

// ---------------- layernorm: fp32 row (D_) -> bf16 row ----------------
__global__ __launch_bounds__(256) void k_layernorm(
    const float* __restrict__ x, const float* __restrict__ gamma,
    const float* __restrict__ beta, unsigned short* __restrict__ out) {
    int row = blockIdx.x;
    int t = threadIdx.x;
    const float* xr = x + (size_t)row * D_;
    float4 v = ((const float4*)xr)[t];
    float s = v.x + v.y + v.z + v.w;
    float q = v.x * v.x + v.y * v.y + v.z * v.z + v.w * v.w;
#pragma unroll
    for (int off = 32; off; off >>= 1) {
        s += __shfl_down(s, off);
        q += __shfl_down(q, off);
    }
    __shared__ float ls[4], lq[4];
    int wv = t >> 6;
    if ((t & 63) == 0) { ls[wv] = s; lq[wv] = q; }
    __syncthreads();
    if (t == 0) {
        float S = ls[0] + ls[1] + ls[2] + ls[3];
        float Q = lq[0] + lq[1] + lq[2] + lq[3];
        float mean = S * (1.0f / D_);
        float var = Q * (1.0f / D_) - mean * mean;
        ls[0] = mean; lq[0] = rsqrtf(var + 1e-5f);
    }
    __syncthreads();
    float mean = ls[0], rstd = lq[0];
    float4 g = ((const float4*)gamma)[t];
    float4 b = ((const float4*)beta)[t];
    ushort4 o;
    o.x = f2bf(g.x * (v.x - mean) * rstd + b.x);
    o.y = f2bf(g.y * (v.y - mean) * rstd + b.y);
    o.z = f2bf(g.z * (v.z - mean) * rstd + b.z);
    o.w = f2bf(g.w * (v.w - mean) * rstd + b.w);
    ((ushort4*)(out + (size_t)row * D_))[t] = o;
}

// ---------------- causal softmax, in-place on bf16 scores rows ----------------
// Vectorized 16B/lane (bf16x8); thread t owns elems 8t..8t+7.
// Causal truncation: read only j < valid; write only j < roundup(valid,128).
__global__ __launch_bounds__(256) void k_softmax(unsigned short* __restrict__ sp) {
    int r = blockIdx.x;          // global row in [0, B_*S_)
    int i = r & (S_ - 1);        // query index within batch
    unsigned short* row = sp + (size_t)r * S_;
    int t = threadIdx.x;
    int valid = i + 1;
    int wlim = (valid + 127) & ~127;  // multiple of 128 (and of 8)
    bf16x8 v8 = {};
    if (t * 8 < valid) v8 = *(const bf16x8*)(row + t * 8);
    float vals[8];
    float mx = -1e30f;
#pragma unroll
    for (int k = 0; k < 8; k++) {
        int j = t * 8 + k;
        vals[k] = (j < valid) ? bf2f((unsigned short)v8[k]) : -1e30f;
        mx = fmaxf(mx, vals[k]);
    }
#pragma unroll
    for (int off = 32; off; off >>= 1) mx = fmaxf(mx, __shfl_xor(mx, off));
    __shared__ float red[4];
    if ((t & 63) == 0) red[t >> 6] = mx;
    __syncthreads();
    mx = fmaxf(fmaxf(red[0], red[1]), fmaxf(red[2], red[3]));
    __syncthreads();
    float e[8];
    float sum = 0.f;
#pragma unroll
    for (int k = 0; k < 8; k++) {
        int j = t * 8 + k;
        e[k] = (j < valid) ? __expf(vals[k] - mx) : 0.f;
        sum += e[k];
    }
#pragma unroll
    for (int off = 32; off; off >>= 1) sum += __shfl_xor(sum, off);
    if ((t & 63) == 0) red[t >> 6] = sum;
    __syncthreads();
    sum = red[0] + red[1] + red[2] + red[3];
    float inv = 1.0f / sum;
    if (t * 8 < wlim) {
        bf16x8 o8;
#pragma unroll
        for (int k = 0; k < 8; k++) o8[k] = (short)f2bf(e[k] * inv);
        *(bf16x8*)(row + t * 8) = o8;
    }
}

// ---------------- GEMM (legacy 128x128, 2-phase counted-vmcnt) ----------------
// Used for PV (klimit) and FFN2 (N=1024). 64KB LDS -> 2 blocks/CU: cross-block
// TLP fills barrier gaps — empirically beats every 1-block/CU deep schedule
// tried for long-K skinny shapes (rounds 3-5).
template <int EPI>
__global__ __launch_bounds__(256) void k_gemm_bt(
    const unsigned short* __restrict__ A, const unsigned short* __restrict__ Bt,
    void* __restrict__ Cv, const float* __restrict__ bias, const float* __restrict__ res,
    int K, int lda, int ldb, int ldc,
    long long sA, long long sB, long long sC, float scale, int klimit, int swz) {
    int bn, bm, z;
    if (swz > 0) {
        int GN = gridDim.x, GM = gridDim.y;
        int L = blockIdx.x + GN * (blockIdx.y + GM * blockIdx.z);
        int rows = gridDim.y * gridDim.z;
        int xcd = L & 7;
        int s = L >> 3;
        int bng = GN / swz;
        int rpg = rows * swz / 8;
        int xg = xcd % swz, yg = xcd / swz;
        int bnl = s % bng;
        int rl = s / bng;
        int row = yg * rpg + rl;
        bn = xg * bng + bnl;
        bm = row % GM;
        z = row / GM;
    } else {
        bn = blockIdx.x; bm = blockIdx.y; z = blockIdx.z;
    }
    if (EPI == 1 && bn > bm) return;
    A += (long long)z * sA;
    Bt += (long long)z * sB;
    long long coff = (long long)z * sC;
    float* Cf = (float*)Cv;
    unsigned short* Cb = (unsigned short*)Cv;

    __shared__ unsigned short As[2][2][128 * 32];
    __shared__ unsigned short Bs[2][2][128 * 32];

    int t = threadIdx.x;
    int l = t & 63, w = t >> 6;
    int wm = (w & 1) * 64, wn = (w >> 1) * 64;
    int lr = l & 15, lq = l >> 4;

    f32x4 acc[4][4];
#pragma unroll
    for (int i = 0; i < 4; i++)
#pragma unroll
        for (int j = 0; j < 4; j++) acc[i][j] = (f32x4){0.f, 0.f, 0.f, 0.f};

    int kend = K;
    if (klimit) { int ke = (bm + 1) * 128; kend = ke < K ? ke : K; }

    int sr = l >> 2;
    int sc = (l & 3) * 8;
    const unsigned short* gA0 = A + (size_t)(bm * 128 + w * 32 + sr) * lda + sc;
    const unsigned short* gA1 = gA0 + (size_t)16 * lda;
    const unsigned short* gB0 = Bt + (size_t)(bn * 128 + w * 32 + sr) * ldb + sc;
    const unsigned short* gB1 = gB0 + (size_t)16 * ldb;

    auto stage = [&](int buf, int k0) {
#pragma unroll
        for (int kc = 0; kc < 2; kc++) {
            int kk = k0 + kc * 32;
            gld16(gA0 + kk, &As[buf][kc][(w * 32) * 32]);
            gld16(gA1 + kk, &As[buf][kc][(w * 32 + 16) * 32]);
            gld16(gB0 + kk, &Bs[buf][kc][(w * 32) * 32]);
            gld16(gB1 + kk, &Bs[buf][kc][(w * 32 + 16) * 32]);
        }
    };

    int NB = kend >> 6;
    stage(0, 0);
    for (int it = 0; it < NB; it++) {
        int cur = it & 1;
        if (it + 1 < NB) {
            stage(1 - cur, (it + 1) * 64);
            WAIT_VM8();
        } else {
            WAIT_VM0();
        }
        __builtin_amdgcn_s_barrier();
#pragma unroll
        for (int kc = 0; kc < 2; kc++) {
            bf16x8 af[4], bf[4];
#pragma unroll
            for (int i = 0; i < 4; i++)
                af[i] = *(const bf16x8*)(&As[cur][kc][(wm + i * 16 + lr) * 32 + lq * 8]);
#pragma unroll
            for (int j = 0; j < 4; j++)
                bf[j] = *(const bf16x8*)(&Bs[cur][kc][(wn + j * 16 + lr) * 32 + lq * 8]);
#pragma unroll
            for (int i = 0; i < 4; i++)
#pragma unroll
                for (int j = 0; j < 4; j++)
                    acc[i][j] = __builtin_amdgcn_mfma_f32_16x16x32_bf16(af[i], bf[j], acc[i][j], 0, 0, 0);
        }
        __builtin_amdgcn_s_barrier();
    }

#pragma unroll
    for (int i = 0; i < 4; i++) {
        int mbase = bm * 128 + wm + i * 16 + lq * 4;
#pragma unroll
        for (int j = 0; j < 4; j++) {
            int n = bn * 128 + wn + j * 16 + lr;
#pragma unroll
            for (int r = 0; r < 4; r++) {
                int m = mbase + r;
                float v = acc[i][j][r];
                long long idx = coff + (long long)m * ldc + n;
                if (EPI == 0) {
                    Cb[idx] = f2bf(v);
                } else if (EPI == 1) {
                    Cb[idx] = f2bf(v * scale);
                } else if (EPI == 2) {
                    Cf[idx] = v + res[idx];
                } else if (EPI == 3) {
                    float u = v + bias[n];
                    Cb[idx] = f2bf(u > 0.f ? u : 0.f);
                } else {
                    Cf[idx] = v + bias[n] + res[idx];
                }
            }
        }
    }
}

// ---------------- GEMM 256x256, 8-wave, BK=64, 4-phase/K-tile ----------------
// (verified round 2) T2 3-bit XOR swizzle both-sides, T3+T4 counted vmcnt(6),
// T5 setprio. Used for QKV / scores / FFN1.
// Round-10: XCD-colocating swz (same bijection as legacy kernel) — default
// bn-fastest dispatch scatters panel-sharers across XCD L2s (QKV FETCH 79MB
// vs 23 ideal, FFN1 74 vs 25). swz groups each XCD onto a bn-group x bm-stripe.
// EPI=6: fused QKV epilogue. Block-uniform split at bn=8 (n=2048 boundary):
//   bn<8 : Q,K tile -> row-major into C (ldc 3072).
//   bn>=8: V tile -> VT via per-wave LDS transpose (round-9, verified).
template <int EPI>
__global__ __launch_bounds__(512, 2) void k_gemm256(
    const unsigned short* __restrict__ A, const unsigned short* __restrict__ Bt,
    void* __restrict__ Cv, const float* __restrict__ bias, const float* __restrict__ res,
    int K, int lda, int ldb, int ldc,
    long long sA, long long sB, long long sC, float scale, int klimit, int swz) {
    int bn, bm, z;
    if (swz > 0) {
        int GN = gridDim.x, GM = gridDim.y;
        int L = blockIdx.x + GN * (blockIdx.y + GM * blockIdx.z);
        int rows = gridDim.y * gridDim.z;
        int xcd = L & 7;
        int s = L >> 3;
        int bng = GN / swz;
        int rpg = rows * swz / 8;
        int xg = xcd % swz, yg = xcd / swz;
        int bnl = s % bng;
        int rl = s / bng;
        int row = yg * rpg + rl;
        bn = xg * bng + bnl;
        bm = row % GM;
        z = row / GM;
    } else {
        bn = blockIdx.x; bm = blockIdx.y; z = blockIdx.z;
    }
    if (EPI == 1 && bn > bm) return;  // fully-masked causal block
    A += (long long)z * sA;
    Bt += (long long)z * sB;
    long long coff = (long long)z * sC;
    float* Cf = (float*)Cv;
    unsigned short* Cb = (unsigned short*)Cv;

    __shared__ unsigned short As[2][2][128 * 64];
    __shared__ unsigned short Bs[2][2][128 * 64];

    int t = threadIdx.x;
    int l = t & 63, w = t >> 6;       // lane, wave 0..7 (2M x 4N)
    int wmh = w >> 2;                 // which A half this wave reads
    int wnh = (w >> 1) & 1;           // which B half this wave reads
    int bnl2 = (w & 1) * 64;          // row base within that B half
    int lr = l & 15, lq = l >> 4;
    int rx = (lr & 7) << 3;           // read-side swizzle XOR (elems)
    int c0 = lq * 8;                  // un-swizzled k-subcolumn (elems)

    f32x4 acc[8][4];
#pragma unroll
    for (int i = 0; i < 8; i++)
#pragma unroll
        for (int j = 0; j < 4; j++) acc[i][j] = (f32x4){0.f, 0.f, 0.f, 0.f};

    int kend = K;
    if (klimit) { int ke = (bm + 1) * 256; kend = ke < K ? ke : K; }
    int NB = kend >> 6;

    int grow = l >> 3;
    int gcol = ((l & 7) * 8) ^ (((l >> 3) & 7) << 3);
    const unsigned short* gA = A + (size_t)(bm * 256 + w * 16 + grow) * lda + gcol;
    const unsigned short* gB = Bt + (size_t)(bn * 256 + w * 16 + grow) * ldb + gcol;

    auto stageA = [&](int buf, int half, int k0) {
        const unsigned short* g = gA + (size_t)(half * 128) * lda + k0;
        unsigned short* s = &As[buf][half][(w * 16) * 64];
        gld16(g, s);
        gld16(g + (size_t)8 * lda, s + 8 * 64);
    };
    auto stageB = [&](int buf, int half, int k0) {
        const unsigned short* g = gB + (size_t)(half * 128) * ldb + k0;
        unsigned short* s = &Bs[buf][half][(w * 16) * 64];
        gld16(g, s);
        gld16(g + (size_t)8 * ldb, s + 8 * 64);
    };

    stageA(0, 0, 0); stageA(0, 1, 0);
    stageB(0, 0, 0); stageB(0, 1, 0);
    int kp = (NB > 1) ? 64 : 0;
    stageB(1, 0, kp); stageB(1, 1, kp); stageA(1, 0, kp);
    WAIT_VM6();
    __builtin_amdgcn_s_barrier();

    bf16x8 aF0[2][4], aF1[2][4], bF[2][4];  // [kchunk][frag]

    for (int j = 0; j < NB; j++) {
        int b = j & 1;
        int k1 = ((j + 1 < NB) ? (j + 1) : (NB - 1)) << 6;
        int k2 = ((j + 2 < NB) ? (j + 2) : (NB - 1)) << 6;
        const unsigned short* Ah = &As[b][wmh][0];
        const unsigned short* Bh = &Bs[b][wnh][0];

        // ---- P1 ----
#pragma unroll
        for (int kc = 0; kc < 2; kc++) {
#pragma unroll
            for (int f = 0; f < 4; f++)
                bF[kc][f] = *(const bf16x8*)(Bh + (bnl2 + f * 16 + lr) * 64 + ((kc * 32 + c0) ^ rx));
#pragma unroll
            for (int f = 0; f < 4; f++)
                aF0[kc][f] = *(const bf16x8*)(Ah + (f * 16 + lr) * 64 + ((kc * 32 + c0) ^ rx));
        }
        stageA(b ^ 1, 1, k1);
        __builtin_amdgcn_s_barrier();
        __builtin_amdgcn_s_setprio(1);
#pragma unroll
        for (int kc = 0; kc < 2; kc++)
#pragma unroll
            for (int i = 0; i < 4; i++)
#pragma unroll
                for (int jn = 0; jn < 2; jn++)
                    acc[i][jn] = __builtin_amdgcn_mfma_f32_16x16x32_bf16(
                        aF0[kc][i], bF[kc][jn], acc[i][jn], 0, 0, 0);
        __builtin_amdgcn_s_setprio(0);
        __builtin_amdgcn_s_barrier();

        // ---- P2 ----
#pragma unroll
        for (int kc = 0; kc < 2; kc++)
#pragma unroll
            for (int f = 0; f < 4; f++)
                aF1[kc][f] = *(const bf16x8*)(Ah + (64 + f * 16 + lr) * 64 + ((kc * 32 + c0) ^ rx));
        stageB(b, 0, k2);
        __builtin_amdgcn_s_barrier();
        __builtin_amdgcn_s_setprio(1);
#pragma unroll
        for (int kc = 0; kc < 2; kc++)
#pragma unroll
            for (int i = 0; i < 4; i++)
#pragma unroll
                for (int jn = 0; jn < 2; jn++)
                    acc[4 + i][jn] = __builtin_amdgcn_mfma_f32_16x16x32_bf16(
                        aF1[kc][i], bF[kc][jn], acc[4 + i][jn], 0, 0, 0);
        __builtin_amdgcn_s_setprio(0);
        __builtin_amdgcn_s_barrier();

        // ---- P3 ----
        stageB(b, 1, k2);
        __builtin_amdgcn_s_barrier();
        __builtin_amdgcn_s_setprio(1);
#pragma unroll
        for (int kc = 0; kc < 2; kc++)
#pragma unroll
            for (int i = 0; i < 4; i++)
#pragma unroll
                for (int jn = 0; jn < 2; jn++)
                    acc[4 + i][2 + jn] = __builtin_amdgcn_mfma_f32_16x16x32_bf16(
                        aF1[kc][i], bF[kc][2 + jn], acc[4 + i][2 + jn], 0, 0, 0);
        __builtin_amdgcn_s_setprio(0);
        __builtin_amdgcn_s_barrier();

        // ---- P4 ----
        stageA(b, 0, k2);
        WAIT_VM6();
        __builtin_amdgcn_s_barrier();
        __builtin_amdgcn_s_setprio(1);
#pragma unroll
        for (int kc = 0; kc < 2; kc++)
#pragma unroll
            for (int i = 0; i < 4; i++)
#pragma unroll
                for (int jn = 0; jn < 2; jn++)
                    acc[i][2 + jn] = __builtin_amdgcn_mfma_f32_16x16x32_bf16(
                        aF0[kc][i], bF[kc][2 + jn], acc[i][2 + jn], 0, 0, 0);
        __builtin_amdgcn_s_setprio(0);
        __builtin_amdgcn_s_barrier();
    }
    WAIT_VM0();

    if (EPI == 6 && bn >= 8) {
        // ---- V block: per-wave LDS transpose -> coalesced VT stores ----
        __builtin_amdgcn_s_barrier();  // all waves drained their gld16 (vm0 above)
        unsigned short* T = (w < 4) ? (unsigned short*)As + (size_t)w * 8192
                                    : (unsigned short*)Bs + (size_t)(w - 4) * 8192;
        // write: wave's 64n x 128m sub-tile, [n][m] layout, 8-elem-slot XOR swz
#pragma unroll
        for (int i = 0; i < 8; i++)
#pragma unroll
            for (int jn = 0; jn < 4; jn++) {
                int nl = jn * 16 + lr;          // 0..63
                int ml = i * 16 + lq * 4;       // 0..127, 4-aligned
                ushort4 o;
                o.x = f2bf(acc[i][jn][0]);
                o.y = f2bf(acc[i][jn][1]);
                o.z = f2bf(acc[i][jn][2]);
                o.w = f2bf(acc[i][jn][3]);
                *(ushort4*)&T[nl * 128 + (((ml & ~7) ^ ((nl & 7) << 3)) | (ml & 7))] = o;
            }
        WAIT_LGKM0();
        __builtin_amdgcn_s_barrier();
        // read rows + coalesced store: 16 passes, 4 rows x 16 lanes x 16B each
        unsigned short* VTp = (unsigned short*)(size_t)res;
        int batch = (bm * 256) >> 11;
        size_t mb0 = (size_t)((bm * 256) & 2047) + (size_t)wmh * 128;
        size_t nb0 = (size_t)(bn * 256 - 2048 + (w & 3) * 64);
        size_t vbase = (size_t)batch * D_ * S_ + mb0;
#pragma unroll
        for (int p = 0; p < 16; p++) {
            int nl = p * 4 + (l >> 4);
            int mo = (l & 15) * 8;
            bf16x8 v = *(const bf16x8*)&T[nl * 128 + (mo ^ ((nl & 7) << 3))];
            *(bf16x8*)(VTp + vbase + (nb0 + nl) * S_ + mo) = v;
        }
    } else {
#pragma unroll
        for (int i = 0; i < 8; i++) {
            int mbase = bm * 256 + wmh * 128 + i * 16 + lq * 4;
#pragma unroll
            for (int jn = 0; jn < 4; jn++) {
                int n = bn * 256 + (w & 3) * 64 + jn * 16 + lr;
#pragma unroll
                for (int r = 0; r < 4; r++) {
                    int m = mbase + r;
                    float v = acc[i][jn][r];
                    long long idx = coff + (long long)m * ldc + n;
                    if (EPI == 0 || EPI == 6) {
                        Cb[idx] = f2bf(v);
                    } else if (EPI == 1) {
                        Cb[idx] = f2bf(v * scale);
                    } else if (EPI == 2) {
                        Cf[idx] = v + res[idx];
                    } else if (EPI == 3) {
                        float u = v + bias[n];
                        Cb[idx] = f2bf(u > 0.f ? u : 0.f);
                    } else {  // EPI == 4
                        Cf[idx] = v + bias[n] + res[idx];
                    }
                }
            }
        }
    }
}

extern "C" void kernel_launch(void* const* d_in, const int* in_sizes, int n_in,
                              void* d_out, int out_size, void* d_ws, size_t ws_size,
                              hipStream_t stream) {
    const float* x      = (const float*)d_in[0];
    const float* Qw     = (const float*)d_in[1];
    const float* Kw     = (const float*)d_in[2];
    const float* Vw     = (const float*)d_in[3];
    const float* w1     = (const float*)d_in[4];
    const float* b1     = (const float*)d_in[5];
    const float* w2     = (const float*)d_in[6];
    const float* b2     = (const float*)d_in[7];
    const float* gamma1 = (const float*)d_in[8];
    const float* beta1  = (const float*)d_in[9];
    const float* gamma2 = (const float*)d_in[10];
    const float* beta2  = (const float*)d_in[11];
    float* out = (float*)d_out;

    char* ws = (char*)d_ws;
    size_t off = 0;
    auto alloc = [&](size_t bytes) -> void* {
        void* p = ws + off;
        off += (bytes + 255) & ~(size_t)255;
        return p;
    };
    const size_t MN = (size_t)B_ * S_ * D_;  // 8.4M elems
    unsigned short* xn     = (unsigned short*)alloc(MN * 2);                     // 16.8MB
    unsigned short* scoreP = (unsigned short*)alloc((size_t)B_ * S_ * S_ * 2);   // 33.6MB, scores->P in place
    unsigned short* qkv    = (unsigned short*)alloc((size_t)B_ * S_ * 3072 * 2); // 50.3MB interleaved Q|K|(V unused)
    unsigned short* VT     = (unsigned short*)alloc(MN * 2);                     // 16.8MB
    unsigned short* QKVwT  = (unsigned short*)alloc((size_t)3 * D_ * D_ * 2);    // 6.3MB
    unsigned short* w1T    = (unsigned short*)alloc((size_t)D_ * F_ * 2);        // 8.4MB
    unsigned short* w2T    = (unsigned short*)alloc((size_t)F_ * D_ * 2);        // 8.4MB
    // mid (8192 x 4096 bf16 = 67,108,864 B) overlays qkv+VT (dead after PV).
    unsigned short* mid = qkv;

    // fused weight conversion (1 launch; transposed so all GEMMs take Bt = N x K)
    k_transpose_weights<<<11264, dim3(32, 8), 0, stream>>>(
        Qw, Kw, Vw, w1, w2, QKVwT, w1T, w2T);

    // LN1
    k_layernorm<<<B_ * S_, 256, 0, stream>>>(x, gamma1, beta1, xn);

    // fused QKV projection: M = 8192, N = 3072, K = 1024. Q,K -> qkv row-major
    // (ldc 3072); V -> VT directly transposed (EPI=6, VT via res; LDS-transposed
    // coalesced stores). XCD swz=2: each XCD gets 6 bn x 8 bm (panel reuse in L2).
    const int Mtok = B_ * S_;
    k_gemm256<6><<<dim3(3072 / 256, Mtok / 256), 512, 0, stream>>>(
        xn, QKVwT, qkv, nullptr, (const float*)VT, D_, D_, D_, 3072, 0, 0, 0, 1.f, 0, 2);

    // scores = Q @ K^T / 32 (batched, bf16 out), upper-tri blocks skipped
    // (swz=0: causal skip makes remaps imbalanced; all 144 active fit anyway)
    k_gemm256<1><<<dim3(S_ / 256, S_ / 256, B_), 512, 0, stream>>>(
        qkv, qkv + 1024, scoreP, nullptr, nullptr, D_, 3072, 3072, S_,
        (long long)S_ * 3072, (long long)S_ * 3072, (long long)S_ * S_, 0.03125f, 0, 0);

    // causal softmax in place -> P (bf16), truncated to lower-tri + pad
    k_softmax<<<B_ * S_, 256, 0, stream>>>(scoreP);

    // attn = P @ V + x -> out (fp32); K-loop truncated at diagonal (mult of 64)
    k_gemm_bt<2><<<dim3(D_ / 128, S_ / 128, B_), 256, 0, stream>>>(
        scoreP, VT, out, nullptr, x, S_, S_, S_, D_,
        (long long)S_ * S_, (long long)D_ * S_, (long long)S_ * D_, 1.f, 1, 2);

    // LN2 on out -> xn (h)
    k_layernorm<<<B_ * S_, 256, 0, stream>>>(out, gamma2, beta2, xn);

    // mid = relu(h @ w1 + b1) (bf16), 256^2 4-phase: grid 16x32 = 512 blocks,
    // XCD swz=2: each XCD gets 8 bn x 8 bm (A/B panel reuse in L2)
    k_gemm256<3><<<dim3(F_ / 256, Mtok / 256), 512, 0, stream>>>(
        xn, w1T, mid, b1, nullptr, D_, D_, D_, F_, 0, 0, 0, 1.f, 0, 2);

    // out = out + mid @ w2 + b2 (legacy 128^2, 2 blocks/CU — best known for
    // this shape; rounds 3-5 A/B'd three deeper 1-block/CU schedules, all lost)
    k_gemm_bt<4><<<dim3(D_ / 128, Mtok / 128), 256, 0, stream>>>(
        mid, w2T, out, b2, out, F_, F_, F_, D_, 0, 0, 0, 1.f, 0, 2);
}

// Round 11
// 455.070 us; speedup vs baseline: 1.0455x; 1.0053x over previous
//
#include <hip/hip_runtime.h>
#include <hip/hip_bf16.h>

#define B_ 4
#define S_ 2048
#define D_ 1024
#define F_ 4096

typedef short bf16x8 __attribute__((ext_vector_type(8)));
typedef float f32x4 __attribute__((ext_vector_type(4)));

static __device__ __forceinline__ unsigned short f2bf(float f) {
    union { float f; unsigned int u; } v; v.f = f;
    unsigned int u = v.u + 0x7FFF + ((v.u >> 16) & 1);  // RNE
    return (unsigned short)(u >> 16);
}
static __device__ __forceinline__ float bf2f(unsigned short u) {
    union { unsigned int u; float f; } v; v.u = ((unsigned int)u) << 16;
    return v.f;
}

// async global->LDS, 16B per lane. LDS dest is wave-uniform base + lane*16.
typedef const __attribute__((address_space(1))) unsigned int* gp_t;
typedef __attribute__((address_space(3))) unsigned int* lp_t;
static __device__ __forceinline__ void gld16(const unsigned short* g, unsigned short* l) {
    __builtin_amdgcn_global_load_lds((gp_t)g, (lp_t)l, 16, 0, 0);
}

// s_waitcnt with selected counters masked off (gfx9 encoding:
// vmcnt[3:0]|[15:14], expcnt[6:4], lgkmcnt[11:8])
#define WAIT_VM8()   __builtin_amdgcn_s_waitcnt(0x0F78)
#define WAIT_VM6()   __builtin_amdgcn_s_waitcnt(0x0F76)
#define WAIT_VM0()   __builtin_amdgcn_s_waitcnt(0x0F70)
#define WAIT_LGKM0() __builtin_amdgcn_s_waitcnt(0xC07F)  // lgkmcnt(0) only

// ---------------- fused prologue: 5 weight transposes + LN1 ------------------
// One launch (round-11): blocks [0,11264) = weight transposes (fp32 -> bf16,
// transposed); blocks [11264, 11264+8192) = LN1 rows (x -> xn). The two halves
// are independent; fusing removes a launch gap and overlaps two memory-bound
// kernels' machine-fill tails. All blocks are 256 threads (dim3(32,8)).
__global__ __launch_bounds__(256) void k_prologue(
    const float* __restrict__ Qw, const float* __restrict__ Kw,
    const float* __restrict__ Vw, const float* __restrict__ w1,
    const float* __restrict__ w2, unsigned short* __restrict__ QKVwT,
    unsigned short* __restrict__ w1T, unsigned short* __restrict__ w2T,
    const float* __restrict__ x, const float* __restrict__ gamma,
    const float* __restrict__ beta, unsigned short* __restrict__ xn) {
    int id = blockIdx.x;
    if (id < 11264) {
        // ---- weight transpose tile ----
        __shared__ float tl[32][33];
        const float* in;
        unsigned short* out;
        int R, C, bx, by;
        if (id < 3072) {
            int z = id >> 10, r = id & 1023;
            in = (z == 0) ? Qw : (z == 1) ? Kw : Vw;
            out = QKVwT + (size_t)z * D_ * D_;
            R = D_; C = D_; bx = r & 31; by = r >> 5;
        } else if (id < 7168) {
            int r = id - 3072;
            in = w1; out = w1T; R = D_; C = F_;
            bx = r & 127; by = r >> 7;   // (C/32=128) x (R/32=32)
        } else {
            int r = id - 7168;
            in = w2; out = w2T; R = F_; C = D_;
            bx = r & 31; by = r >> 5;    // (C/32=32) x (R/32=128)
        }
        int c0 = bx * 32, r0 = by * 32;
        int xx = threadIdx.x, yy = threadIdx.y;  // 32 x 8
#pragma unroll
        for (int i = 0; i < 4; i++)
            tl[yy + 8 * i][xx] = in[(size_t)(r0 + yy + 8 * i) * C + c0 + xx];
        __syncthreads();
#pragma unroll
        for (int i = 0; i < 4; i++)
            out[(size_t)(c0 + yy + 8 * i) * R + r0 + xx] = f2bf(tl[xx][yy + 8 * i]);
    } else {
        // ---- LN1 row ----
        int row = id - 11264;
        int t = threadIdx.x + 32 * threadIdx.y;  // flat 0..255, consecutive
        const float* xr = x + (size_t)row * D_;
        float4 v = ((const float4*)xr)[t];
        float s = v.x + v.y + v.z + v.w;
        float q = v.x * v.x + v.y * v.y + v.z * v.z + v.w * v.w;
#pragma unroll
        for (int off = 32; off; off >>= 1) {
            s += __shfl_down(s, off);
            q += __shfl_down(q, off);
        }
        __shared__ float ls[4], lq[4];
        int wv = t >> 6;
        if ((t & 63) == 0) { ls[wv] = s; lq[wv] = q; }
        __syncthreads();
        if (t == 0) {
            float S = ls[0] + ls[1] + ls[2] + ls[3];
            float Q = lq[0] + lq[1] + lq[2] + lq[3];
            float mean = S * (1.0f / D_);
            float var = Q * (1.0f / D_) - mean * mean;
            ls[0] = mean; lq[0] = rsqrtf(var + 1e-5f);
        }
        __syncthreads();
        float mean = ls[0], rstd = lq[0];
        float4 g = ((const float4*)gamma)[t];
        float4 b = ((const float4*)beta)[t];
        ushort4 o;
        o.x = f2bf(g.x * (v.x - mean) * rstd + b.x);
        o.y = f2bf(g.y * (v.y - mean) * rstd + b.y);
        o.z = f2bf(g.z * (v.z - mean) * rstd + b.z);
        o.w = f2bf(g.w * (v.w - mean) * rstd + b.w);
        ((ushort4*)(xn + (size_t)row * D_))[t] = o;
    }
}

// ---------------- layernorm: fp32 row (D_) -> bf16 row ----------------
__global__ __launch_bounds__(256) void k_layernorm(
    const float* __restrict__ x, const float* __restrict__ gamma,
    const float* __restrict__ beta, unsigned short* __restrict__ out) {
    int row = blockIdx.x;
    int t = threadIdx.x;
    const float* xr = x + (size_t)row * D_;
    float4 v = ((const float4*)xr)[t];
    float s = v.x + v.y + v.z + v.w;
    float q = v.x * v.x + v.y * v.y + v.z * v.z + v.w * v.w;
#pragma unroll
    for (int off = 32; off; off >>= 1) {
        s += __shfl_down(s, off);
        q += __shfl_down(q, off);
    }
    __shared__ float ls[4], lq[4];
    int wv = t >> 6;
    if ((t & 63) == 0) { ls[wv] = s; lq[wv] = q; }
    __syncthreads();
    if (t == 0) {
        float S = ls[0] + ls[1] + ls[2] + ls[3];
        float Q = lq[0] + lq[1] + lq[2] + lq[3];
        float mean = S * (1.0f / D_);
        float var = Q * (1.0f / D_) - mean * mean;
        ls[0] = mean; lq[0] = rsqrtf(var + 1e-5f);
    }
    __syncthreads();
    float mean = ls[0], rstd = lq[0];
    float4 g = ((const float4*)gamma)[t];
    float4 b = ((const float4*)beta)[t];
    ushort4 o;
    o.x = f2bf(g.x * (v.x - mean) * rstd + b.x);
    o.y = f2bf(g.y * (v.y - mean) * rstd + b.y);
    o.z = f2bf(g.z * (v.z - mean) * rstd + b.z);
    o.w = f2bf(g.w * (v.w - mean) * rstd + b.w);
    ((ushort4*)(out + (size_t)row * D_))[t] = o;
}

// ---------------- causal softmax, in-place on bf16 scores rows ----------------
// Vectorized 16B/lane (bf16x8); thread t owns elems 8t..8t+7.
// Causal truncation: read only j < valid; write only j < roundup(valid,128).
__global__ __launch_bounds__(256) void k_softmax(unsigned short* __restrict__ sp) {
    int r = blockIdx.x;          // global row in [0, B_*S_)
    int i = r & (S_ - 1);        // query index within batch
    unsigned short* row = sp + (size_t)r * S_;
    int t = threadIdx.x;
    int valid = i + 1;
    int wlim = (valid + 127) & ~127;  // multiple of 128 (and of 8)
    bf16x8 v8 = {};
    if (t * 8 < valid) v8 = *(const bf16x8*)(row + t * 8);
    float vals[8];
    float mx = -1e30f;
#pragma unroll
    for (int k = 0; k < 8; k++) {
        int j = t * 8 + k;
        vals[k] = (j < valid) ? bf2f((unsigned short)v8[k]) : -1e30f;
        mx = fmaxf(mx, vals[k]);
    }
#pragma unroll
    for (int off = 32; off; off >>= 1) mx = fmaxf(mx, __shfl_xor(mx, off));
    __shared__ float red[4];
    if ((t & 63) == 0) red[t >> 6] = mx;
    __syncthreads();
    mx = fmaxf(fmaxf(red[0], red[1]), fmaxf(red[2], red[3]));
    __syncthreads();
    float e[8];
    float sum = 0.f;
#pragma unroll
    for (int k = 0; k < 8; k++) {
        int j = t * 8 + k;
        e[k] = (j < valid) ? __expf(vals[k] - mx) : 0.f;
        sum += e[k];
    }
#pragma unroll
    for (int off = 32; off; off >>= 1) sum += __shfl_xor(sum, off);
    if ((t & 63) == 0) red[t >> 6] = sum;
    __syncthreads();
    sum = red[0] + red[1] + red[2] + red[3];
    float inv = 1.0f / sum;
    if (t * 8 < wlim) {
        bf16x8 o8;
#pragma unroll
        for (int k = 0; k < 8; k++) o8[k] = (short)f2bf(e[k] * inv);
        *(bf16x8*)(row + t * 8) = o8;
    }
}

// ---------------- GEMM (legacy 128x128, 2-phase counted-vmcnt) ----------------
// Used for PV (klimit) and FFN2 (N=1024). 64KB LDS -> 2 blocks/CU: cross-block
// TLP fills barrier gaps — empirically beats every 1-block/CU deep schedule
// tried for long-K skinny shapes (rounds 3-5).
template <int EPI>
__global__ __launch_bounds__(256) void k_gemm_bt(
    const unsigned short* __restrict__ A, const unsigned short* __restrict__ Bt,
    void* __restrict__ Cv, const float* __restrict__ bias, const float* __restrict__ res,
    int K, int lda, int ldb, int ldc,
    long long sA, long long sB, long long sC, float scale, int klimit, int swz) {
    int bn, bm, z;
    if (swz > 0) {
        int GN = gridDim.x, GM = gridDim.y;
        int L = blockIdx.x + GN * (blockIdx.y + GM * blockIdx.z);
        int rows = gridDim.y * gridDim.z;
        int xcd = L & 7;
        int s = L >> 3;
        int bng = GN / swz;
        int rpg = rows * swz / 8;
        int xg = xcd % swz, yg = xcd / swz;
        int bnl = s % bng;
        int rl = s / bng;
        int row = yg * rpg + rl;
        bn = xg * bng + bnl;
        bm = row % GM;
        z = row / GM;
    } else {
        bn = blockIdx.x; bm = blockIdx.y; z = blockIdx.z;
    }
    if (EPI == 1 && bn > bm) return;
    A += (long long)z * sA;
    Bt += (long long)z * sB;
    long long coff = (long long)z * sC;
    float* Cf = (float*)Cv;
    unsigned short* Cb = (unsigned short*)Cv;

    __shared__ unsigned short As[2][2][128 * 32];
    __shared__ unsigned short Bs[2][2][128 * 32];

    int t = threadIdx.x;
    int l = t & 63, w = t >> 6;
    int wm = (w & 1) * 64, wn = (w >> 1) * 64;
    int lr = l & 15, lq = l >> 4;

    f32x4 acc[4][4];
#pragma unroll
    for (int i = 0; i < 4; i++)
#pragma unroll
        for (int j = 0; j < 4; j++) acc[i][j] = (f32x4){0.f, 0.f, 0.f, 0.f};

    int kend = K;
    if (klimit) { int ke = (bm + 1) * 128; kend = ke < K ? ke : K; }

    int sr = l >> 2;
    int sc = (l & 3) * 8;
    const unsigned short* gA0 = A + (size_t)(bm * 128 + w * 32 + sr) * lda + sc;
    const unsigned short* gA1 = gA0 + (size_t)16 * lda;
    const unsigned short* gB0 = Bt + (size_t)(bn * 128 + w * 32 + sr) * ldb + sc;
    const unsigned short* gB1 = gB0 + (size_t)16 * ldb;

    auto stage = [&](int buf, int k0) {
#pragma unroll
        for (int kc = 0; kc < 2; kc++) {
            int kk = k0 + kc * 32;
            gld16(gA0 + kk, &As[buf][kc][(w * 32) * 32]);
            gld16(gA1 + kk, &As[buf][kc][(w * 32 + 16) * 32]);
            gld16(gB0 + kk, &Bs[buf][kc][(w * 32) * 32]);
            gld16(gB1 + kk, &Bs[buf][kc][(w * 32 + 16) * 32]);
        }
    };

    int NB = kend >> 6;
    stage(0, 0);
    for (int it = 0; it < NB; it++) {
        int cur = it & 1;
        if (it + 1 < NB) {
            stage(1 - cur, (it + 1) * 64);
            WAIT_VM8();
        } else {
            WAIT_VM0();
        }
        __builtin_amdgcn_s_barrier();
#pragma unroll
        for (int kc = 0; kc < 2; kc++) {
            bf16x8 af[4], bf[4];
#pragma unroll
            for (int i = 0; i < 4; i++)
                af[i] = *(const bf16x8*)(&As[cur][kc][(wm + i * 16 + lr) * 32 + lq * 8]);
#pragma unroll
            for (int j = 0; j < 4; j++)
                bf[j] = *(const bf16x8*)(&Bs[cur][kc][(wn + j * 16 + lr) * 32 + lq * 8]);
#pragma unroll
            for (int i = 0; i < 4; i++)
#pragma unroll
                for (int j = 0; j < 4; j++)
                    acc[i][j] = __builtin_amdgcn_mfma_f32_16x16x32_bf16(af[i], bf[j], acc[i][j], 0, 0, 0);
        }
        __builtin_amdgcn_s_barrier();
    }

#pragma unroll
    for (int i = 0; i < 4; i++) {
        int mbase = bm * 128 + wm + i * 16 + lq * 4;
#pragma unroll
        for (int j = 0; j < 4; j++) {
            int n = bn * 128 + wn + j * 16 + lr;
#pragma unroll
            for (int r = 0; r < 4; r++) {
                int m = mbase + r;
                float v = acc[i][j][r];
                long long idx = coff + (long long)m * ldc + n;
                if (EPI == 0) {
                    Cb[idx] = f2bf(v);
                } else if (EPI == 1) {
                    Cb[idx] = f2bf(v * scale);
                } else if (EPI == 2) {
                    Cf[idx] = v + res[idx];
                } else if (EPI == 3) {
                    float u = v + bias[n];
                    Cb[idx] = f2bf(u > 0.f ? u : 0.f);
                } else {
                    Cf[idx] = v + bias[n] + res[idx];
                }
            }
        }
    }
}

// ---------------- GEMM 256x256, 8-wave, BK=64, 4-phase/K-tile ----------------
// (verified round 2) T2 3-bit XOR swizzle both-sides, T3+T4 counted vmcnt(6),
// T5 setprio. Used for QKV / scores / FFN1. Round-10 XCD swz verified (-5us).
// EPI=6: fused QKV epilogue. Block-uniform split at bn=8 (n=2048 boundary):
//   bn<8 : Q,K tile -> row-major into C (ldc 3072).
//   bn>=8: V tile -> VT via per-wave LDS transpose (round-9, verified).
template <int EPI>
__global__ __launch_bounds__(512, 2) void k_gemm256(
    const unsigned short* __restrict__ A, const unsigned short* __restrict__ Bt,
    void* __restrict__ Cv, const float* __restrict__ bias, const float* __restrict__ res,
    int K, int lda, int ldb, int ldc,
    long long sA, long long sB, long long sC, float scale, int klimit, int swz) {
    int bn, bm, z;
    if (swz > 0) {
        int GN = gridDim.x, GM = gridDim.y;
        int L = blockIdx.x + GN * (blockIdx.y + GM * blockIdx.z);
        int rows = gridDim.y * gridDim.z;
        int xcd = L & 7;
        int s = L >> 3;
        int bng = GN / swz;
        int rpg = rows * swz / 8;
        int xg = xcd % swz, yg = xcd / swz;
        int bnl = s % bng;
        int rl = s / bng;
        int row = yg * rpg + rl;
        bn = xg * bng + bnl;
        bm = row % GM;
        z = row / GM;
    } else {
        bn = blockIdx.x; bm = blockIdx.y; z = blockIdx.z;
    }
    if (EPI == 1 && bn > bm) return;  // fully-masked causal block
    A += (long long)z * sA;
    Bt += (long long)z * sB;
    long long coff = (long long)z * sC;
    float* Cf = (float*)Cv;
    unsigned short* Cb = (unsigned short*)Cv;

    __shared__ unsigned short As[2][2][128 * 64];
    __shared__ unsigned short Bs[2][2][128 * 64];

    int t = threadIdx.x;
    int l = t & 63, w = t >> 6;       // lane, wave 0..7 (2M x 4N)
    int wmh = w >> 2;                 // which A half this wave reads
    int wnh = (w >> 1) & 1;           // which B half this wave reads
    int bnl2 = (w & 1) * 64;          // row base within that B half
    int lr = l & 15, lq = l >> 4;
    int rx = (lr & 7) << 3;           // read-side swizzle XOR (elems)
    int c0 = lq * 8;                  // un-swizzled k-subcolumn (elems)

    f32x4 acc[8][4];
#pragma unroll
    for (int i = 0; i < 8; i++)
#pragma unroll
        for (int j = 0; j < 4; j++) acc[i][j] = (f32x4){0.f, 0.f, 0.f, 0.f};

    int kend = K;
    if (klimit) { int ke = (bm + 1) * 256; kend = ke < K ? ke : K; }
    int NB = kend >> 6;

    int grow = l >> 3;
    int gcol = ((l & 7) * 8) ^ (((l >> 3) & 7) << 3);
    const unsigned short* gA = A + (size_t)(bm * 256 + w * 16 + grow) * lda + gcol;
    const unsigned short* gB = Bt + (size_t)(bn * 256 + w * 16 + grow) * ldb + gcol;

    auto stageA = [&](int buf, int half, int k0) {
        const unsigned short* g = gA + (size_t)(half * 128) * lda + k0;
        unsigned short* s = &As[buf][half][(w * 16) * 64];
        gld16(g, s);
        gld16(g + (size_t)8 * lda, s + 8 * 64);
    };
    auto stageB = [&](int buf, int half, int k0) {
        const unsigned short* g = gB + (size_t)(half * 128) * ldb + k0;
        unsigned short* s = &Bs[buf][half][(w * 16) * 64];
        gld16(g, s);
        gld16(g + (size_t)8 * ldb, s + 8 * 64);
    };

    stageA(0, 0, 0); stageA(0, 1, 0);
    stageB(0, 0, 0); stageB(0, 1, 0);
    int kp = (NB > 1) ? 64 : 0;
    stageB(1, 0, kp); stageB(1, 1, kp); stageA(1, 0, kp);
    WAIT_VM6();
    __builtin_amdgcn_s_barrier();

    bf16x8 aF0[2][4], aF1[2][4], bF[2][4];  // [kchunk][frag]

    for (int j = 0; j < NB; j++) {
        int b = j & 1;
        int k1 = ((j + 1 < NB) ? (j + 1) : (NB - 1)) << 6;
        int k2 = ((j + 2 < NB) ? (j + 2) : (NB - 1)) << 6;
        const unsigned short* Ah = &As[b][wmh][0];
        const unsigned short* Bh = &Bs[b][wnh][0];

        // ---- P1 ----
#pragma unroll
        for (int kc = 0; kc < 2; kc++) {
#pragma unroll
            for (int f = 0; f < 4; f++)
                bF[kc][f] = *(const bf16x8*)(Bh + (bnl2 + f * 16 + lr) * 64 + ((kc * 32 + c0) ^ rx));
#pragma unroll
            for (int f = 0; f < 4; f++)
                aF0[kc][f] = *(const bf16x8*)(Ah + (f * 16 + lr) * 64 + ((kc * 32 + c0) ^ rx));
        }
        stageA(b ^ 1, 1, k1);
        __builtin_amdgcn_s_barrier();
        __builtin_amdgcn_s_setprio(1);
#pragma unroll
        for (int kc = 0; kc < 2; kc++)
#pragma unroll
            for (int i = 0; i < 4; i++)
#pragma unroll
                for (int jn = 0; jn < 2; jn++)
                    acc[i][jn] = __builtin_amdgcn_mfma_f32_16x16x32_bf16(
                        aF0[kc][i], bF[kc][jn], acc[i][jn], 0, 0, 0);
        __builtin_amdgcn_s_setprio(0);
        __builtin_amdgcn_s_barrier();

        // ---- P2 ----
#pragma unroll
        for (int kc = 0; kc < 2; kc++)
#pragma unroll
            for (int f = 0; f < 4; f++)
                aF1[kc][f] = *(const bf16x8*)(Ah + (64 + f * 16 + lr) * 64 + ((kc * 32 + c0) ^ rx));
        stageB(b, 0, k2);
        __builtin_amdgcn_s_barrier();
        __builtin_amdgcn_s_setprio(1);
#pragma unroll
        for (int kc = 0; kc < 2; kc++)
#pragma unroll
            for (int i = 0; i < 4; i++)
#pragma unroll
                for (int jn = 0; jn < 2; jn++)
                    acc[4 + i][jn] = __builtin_amdgcn_mfma_f32_16x16x32_bf16(
                        aF1[kc][i], bF[kc][jn], acc[4 + i][jn], 0, 0, 0);
        __builtin_amdgcn_s_setprio(0);
        __builtin_amdgcn_s_barrier();

        // ---- P3 ----
        stageB(b, 1, k2);
        __builtin_amdgcn_s_barrier();
        __builtin_amdgcn_s_setprio(1);
#pragma unroll
        for (int kc = 0; kc < 2; kc++)
#pragma unroll
            for (int i = 0; i < 4; i++)
#pragma unroll
                for (int jn = 0; jn < 2; jn++)
                    acc[4 + i][2 + jn] = __builtin_amdgcn_mfma_f32_16x16x32_bf16(
                        aF1[kc][i], bF[kc][2 + jn], acc[4 + i][2 + jn], 0, 0, 0);
        __builtin_amdgcn_s_setprio(0);
        __builtin_amdgcn_s_barrier();

        // ---- P4 ----
        stageA(b, 0, k2);
        WAIT_VM6();
        __builtin_amdgcn_s_barrier();
        __builtin_amdgcn_s_setprio(1);
#pragma unroll
        for (int kc = 0; kc < 2; kc++)
#pragma unroll
            for (int i = 0; i < 4; i++)
#pragma unroll
                for (int jn = 0; jn < 2; jn++)
                    acc[i][2 + jn] = __builtin_amdgcn_mfma_f32_16x16x32_bf16(
                        aF0[kc][i], bF[kc][2 + jn], acc[i][2 + jn], 0, 0, 0);
        __builtin_amdgcn_s_setprio(0);
        __builtin_amdgcn_s_barrier();
    }
    WAIT_VM0();

    if (EPI == 6 && bn >= 8) {
        // ---- V block: per-wave LDS transpose -> coalesced VT stores ----
        __builtin_amdgcn_s_barrier();  // all waves drained their gld16 (vm0 above)
        unsigned short* T = (w < 4) ? (unsigned short*)As + (size_t)w * 8192
                                    : (unsigned short*)Bs + (size_t)(w - 4) * 8192;
        // write: wave's 64n x 128m sub-tile, [n][m] layout, 8-elem-slot XOR swz
#pragma unroll
        for (int i = 0; i < 8; i++)
#pragma unroll
            for (int jn = 0; jn < 4; jn++) {
                int nl = jn * 16 + lr;          // 0..63
                int ml = i * 16 + lq * 4;       // 0..127, 4-aligned
                ushort4 o;
                o.x = f2bf(acc[i][jn][0]);
                o.y = f2bf(acc[i][jn][1]);
                o.z = f2bf(acc[i][jn][2]);
                o.w = f2bf(acc[i][jn][3]);
                *(ushort4*)&T[nl * 128 + (((ml & ~7) ^ ((nl & 7) << 3)) | (ml & 7))] = o;
            }
        WAIT_LGKM0();
        __builtin_amdgcn_s_barrier();
        // read rows + coalesced store: 16 passes, 4 rows x 16 lanes x 16B each
        unsigned short* VTp = (unsigned short*)(size_t)res;
        int batch = (bm * 256) >> 11;
        size_t mb0 = (size_t)((bm * 256) & 2047) + (size_t)wmh * 128;
        size_t nb0 = (size_t)(bn * 256 - 2048 + (w & 3) * 64);
        size_t vbase = (size_t)batch * D_ * S_ + mb0;
#pragma unroll
        for (int p = 0; p < 16; p++) {
            int nl = p * 4 + (l >> 4);
            int mo = (l & 15) * 8;
            bf16x8 v = *(const bf16x8*)&T[nl * 128 + (mo ^ ((nl & 7) << 3))];
            *(bf16x8*)(VTp + vbase + (nb0 + nl) * S_ + mo) = v;
        }
    } else {
#pragma unroll
        for (int i = 0; i < 8; i++) {
            int mbase = bm * 256 + wmh * 128 + i * 16 + lq * 4;
#pragma unroll
            for (int jn = 0; jn < 4; jn++) {
                int n = bn * 256 + (w & 3) * 64 + jn * 16 + lr;
#pragma unroll
                for (int r = 0; r < 4; r++) {
                    int m = mbase + r;
                    float v = acc[i][jn][r];
                    long long idx = coff + (long long)m * ldc + n;
                    if (EPI == 0 || EPI == 6) {
                        Cb[idx] = f2bf(v);
                    } else if (EPI == 1) {
                        Cb[idx] = f2bf(v * scale);
                    } else if (EPI == 2) {
                        Cf[idx] = v + res[idx];
                    } else if (EPI == 3) {
                        float u = v + bias[n];
                        Cb[idx] = f2bf(u > 0.f ? u : 0.f);
                    } else {  // EPI == 4
                        Cf[idx] = v + bias[n] + res[idx];
                    }
                }
            }
        }
    }
}

extern "C" void kernel_launch(void* const* d_in, const int* in_sizes, int n_in,
                              void* d_out, int out_size, void* d_ws, size_t ws_size,
                              hipStream_t stream) {
    const float* x      = (const float*)d_in[0];
    const float* Qw     = (const float*)d_in[1];
    const float* Kw     = (const float*)d_in[2];
    const float* Vw     = (const float*)d_in[3];
    const float* w1     = (const float*)d_in[4];
    const float* b1     = (const float*)d_in[5];
    const float* w2     = (const float*)d_in[6];
    const float* b2     = (const float*)d_in[7];
    const float* gamma1 = (const float*)d_in[8];
    const float* beta1  = (const float*)d_in[9];
    const float* gamma2 = (const float*)d_in[10];
    const float* beta2  = (const float*)d_in[11];
    float* out = (float*)d_out;

    char* ws = (char*)d_ws;
    size_t off = 0;
    auto alloc = [&](size_t bytes) -> void* {
        void* p = ws + off;
        off += (bytes + 255) & ~(size_t)255;
        return p;
    };
    const size_t MN = (size_t)B_ * S_ * D_;  // 8.4M elems
    unsigned short* xn     = (unsigned short*)alloc(MN * 2);                     // 16.8MB
    unsigned short* scoreP = (unsigned short*)alloc((size_t)B_ * S_ * S_ * 2);   // 33.6MB, scores->P in place
    unsigned short* qkv    = (unsigned short*)alloc((size_t)B_ * S_ * 3072 * 2); // 50.3MB interleaved Q|K|(V unused)
    unsigned short* VT     = (unsigned short*)alloc(MN * 2);                     // 16.8MB
    unsigned short* QKVwT  = (unsigned short*)alloc((size_t)3 * D_ * D_ * 2);    // 6.3MB
    unsigned short* w1T    = (unsigned short*)alloc((size_t)D_ * F_ * 2);        // 8.4MB
    unsigned short* w2T    = (unsigned short*)alloc((size_t)F_ * D_ * 2);        // 8.4MB
    // mid (8192 x 4096 bf16 = 67,108,864 B) overlays qkv+VT (dead after PV).
    unsigned short* mid = qkv;

    // fused prologue: 5 weight transposes + LN1, one launch
    k_prologue<<<11264 + B_ * S_, dim3(32, 8), 0, stream>>>(
        Qw, Kw, Vw, w1, w2, QKVwT, w1T, w2T, x, gamma1, beta1, xn);

    // fused QKV projection: M = 8192, N = 3072, K = 1024. Q,K -> qkv row-major
    // (ldc 3072); V -> VT directly transposed (EPI=6, VT via res; LDS-transposed
    // coalesced stores). XCD swz=2: each XCD gets 6 bn x 8 bm (panel reuse in L2).
    const int Mtok = B_ * S_;
    k_gemm256<6><<<dim3(3072 / 256, Mtok / 256), 512, 0, stream>>>(
        xn, QKVwT, qkv, nullptr, (const float*)VT, D_, D_, D_, 3072, 0, 0, 0, 1.f, 0, 2);

    // scores = Q @ K^T / 32 (batched, bf16 out), upper-tri blocks skipped
    k_gemm256<1><<<dim3(S_ / 256, S_ / 256, B_), 512, 0, stream>>>(
        qkv, qkv + 1024, scoreP, nullptr, nullptr, D_, 3072, 3072, S_,
        (long long)S_ * 3072, (long long)S_ * 3072, (long long)S_ * S_, 0.03125f, 0, 0);

    // causal softmax in place -> P (bf16), truncated to lower-tri + pad
    k_softmax<<<B_ * S_, 256, 0, stream>>>(scoreP);

    // attn = P @ V + x -> out (fp32); K-loop truncated at diagonal (mult of 64)
    k_gemm_bt<2><<<dim3(D_ / 128, S_ / 128, B_), 256, 0, stream>>>(
        scoreP, VT, out, nullptr, x, S_, S_, S_, D_,
        (long long)S_ * S_, (long long)D_ * S_, (long long)S_ * D_, 1.f, 1, 2);

    // LN2 on out -> xn (h)
    k_layernorm<<<B_ * S_, 256, 0, stream>>>(out, gamma2, beta2, xn);

    // mid = relu(h @ w1 + b1) (bf16), 256^2 4-phase: grid 16x32 = 512 blocks,
    // XCD swz=2: each XCD gets 8 bn x 8 bm (A/B panel reuse in L2)
    k_gemm256<3><<<dim3(F_ / 256, Mtok / 256), 512, 0, stream>>>(
        xn, w1T, mid, b1, nullptr, D_, D_, D_, F_, 0, 0, 0, 1.f, 0, 2);

    // out = out + mid @ w2 + b2 (legacy 128^2, 2 blocks/CU — best known for
    // this shape; rounds 3-5 A/B'd three deeper 1-block/CU schedules, all lost)
    k_gemm_bt<4><<<dim3(D_ / 128, Mtok / 128), 256, 0, stream>>>(
        mid, w2T, out, b2, out, F_, F_, F_, D_, 0, 0, 0, 1.f, 0, 2);
}